// Round 14
// baseline (507.084 us; speedup 1.0000x reference)
//
#include <hip/hip_runtime.h>
#include <math.h>

#define BB 32
#define NPGC 256
#define FF 128
#define EDIMC 16
#define ESMC 1280
#define NNODE 8192
#define NEDGE 65536
#define EGC 2048
#define NH 4
#define DH 128
#define HDIM 512
#define SCALE 0.088388347648318447f  // 1/sqrt(128)

typedef __attribute__((ext_vector_type(8))) short bf16x8;
typedef __attribute__((ext_vector_type(4))) float f32x4;

__device__ __forceinline__ float waveReduceSum(float v) {
#pragma unroll
    for (int o = 32; o > 0; o >>= 1) v += __shfl_down(v, o);
    return v;
}

// fp32 -> bf16 (RNE), raw ushort
__device__ __forceinline__ unsigned short f2b(float f) {
    unsigned u = __builtin_bit_cast(unsigned, f);
    return (unsigned short)((u + 0x7fffu + ((u >> 16) & 1u)) >> 16);
}
__device__ __forceinline__ unsigned pack2(float lo, float hi) {
    return (unsigned)f2b(lo) | ((unsigned)f2b(hi) << 16);
}
// packed pair of bf16 (as uint) -> two floats
__device__ __forceinline__ float2 b2f2(unsigned u) {
    float lo = __builtin_bit_cast(float, u << 16);
    float hi = __builtin_bit_cast(float, u & 0xffff0000u);
    return make_float2(lo, hi);
}

// ---------------- FUSED convert + setup -------------------------------------------
__global__ __launch_bounds__(256) void k_convert_setup(
    const float* __restrict__ x, const float* __restrict__ Wq,
    const float* __restrict__ Wk, const float* __restrict__ Wv,
    const float* __restrict__ Wsk, const float* __restrict__ Wt,
    const float* __restrict__ W1, const float* __restrict__ W2,
    unsigned short* __restrict__ xb, unsigned short* __restrict__ wqb,
    unsigned short* __restrict__ wkb, unsigned short* __restrict__ wvb,
    unsigned short* __restrict__ wskb, unsigned short* __restrict__ wtb,
    unsigned short* __restrict__ w1b, unsigned short* __restrict__ w2b,
    const int* __restrict__ dst, int* __restrict__ emask, int* __restrict__ nmask,
    int* __restrict__ coff, int* __restrict__ ceid) {
    __shared__ int cntS[NPGC];
    __shared__ int scanS[NPGC];
    __shared__ int offS[NPGC];
    if (blockIdx.x >= 12800) {
        int g = blockIdx.x - 12800, t = threadIdx.x;
        cntS[t] = 0;
        nmask[g * NPGC + t] = 1;
        __syncthreads();
        int base = g * EGC;
#pragma unroll
        for (int i = 0; i < EGC / 256; ++i) {
            int e = base + i * 256 + t;
            emask[e] = 1;
            atomicAdd(&cntS[dst[e] - g * NPGC], 1);
        }
        __syncthreads();
        scanS[t] = cntS[t];
        __syncthreads();
        for (int off = 1; off < NPGC; off <<= 1) {
            int v = scanS[t];
            if (t >= off) v += scanS[t - off];
            __syncthreads();
            scanS[t] = v;
            __syncthreads();
        }
        int excl = scanS[t] - cntS[t];
        offS[t] = excl;
        coff[g * NPGC + t] = base + excl;
        if (g == 0 && t == 0) coff[NNODE] = NEDGE;
        cntS[t] = 0;
        __syncthreads();
#pragma unroll
        for (int i = 0; i < EGC / 256; ++i) {
            int e = base + i * 256 + t;
            int d = dst[e] - g * NPGC;
            int pos = atomicAdd(&cntS[d], 1);
            ceid[base + offS[d] + pos] = e;
        }
        return;
    }
    int idx = blockIdx.x * 256 + threadIdx.x;
    if (idx < 1048576) { xb[idx] = f2b(x[idx]); return; }
    idx -= 1048576;
    if (idx < 1048576) {  // Wq/Wk/Wv/Wskip: [li][128][512] -> [li][512][128]
        int fam = idx >> 18, local = idx & 262143;
        int li = local >> 16, rem = local & 65535;
        int n = rem >> 7, k = rem & 127;
        const float* S = (fam == 0) ? Wq : (fam == 1) ? Wk : (fam == 2) ? Wv : Wsk;
        unsigned short* D = (fam == 0) ? wqb : (fam == 1) ? wkb : (fam == 2) ? wvb : wskb;
        D[local] = f2b(S[(size_t)li * 65536 + (size_t)k * 512 + n]);
        return;
    }
    idx -= 1048576;
    if (idx < 262144) {  // Wt: [li][512][128] -> [li][128][512]
        int li = idx >> 16, rem = idx & 65535;
        int n = rem >> 9, k = rem & 511;
        wtb[idx] = f2b(Wt[(size_t)li * 65536 + (size_t)k * 128 + n]);
        return;
    }
    idx -= 262144;
    if (idx < 786432) {  // W1: [1536][512] -> [512][1536]
        int n = idx / 1536, k = idx % 1536;
        w1b[idx] = f2b(W1[(size_t)k * 512 + n]);
        return;
    }
    idx -= 786432;
    {  // W2: [512][256] -> [256][512]
        int n = idx >> 9, k = idx & 511;
        w2b[idx] = f2b(W2[(size_t)k * 256 + n]);
    }
}

// ---------------- fused q/k/v/skip GEMM via MFMA bf16 -> bf16 outputs ----------------
__global__ __launch_bounds__(256) void k_qkvs_mfma(
    const unsigned short* __restrict__ hb,
    const unsigned short* __restrict__ wq, const unsigned short* __restrict__ wk,
    const unsigned short* __restrict__ wv, const unsigned short* __restrict__ wsk,
    const float* __restrict__ bq, const float* __restrict__ bk,
    const float* __restrict__ bv, const float* __restrict__ bsk,
    unsigned short* __restrict__ oq, unsigned short* __restrict__ ok,
    unsigned short* __restrict__ ov, unsigned short* __restrict__ osk) {
    const unsigned short* W;
    const float* bias;
    unsigned short* out;
    if (blockIdx.z == 0) { W = wq; bias = bq; out = oq; }
    else if (blockIdx.z == 1) { W = wk; bias = bk; out = ok; }
    else if (blockIdx.z == 2) { W = wv; bias = bv; out = ov; }
    else { W = wsk; bias = bsk; out = osk; }
    int lane = threadIdx.x & 63, wave = threadIdx.x >> 6;
    int quad = lane >> 4, m = lane & 15;
    int xcdx = blockIdx.x;  // [0,64): graph g = (bi&7)+8*((bi>>3)&3), half = bi>>5
    int g = (xcdx & 7) + 8 * ((xcdx >> 3) & 3);
    int half = xcdx >> 5;
    int rowbase = g * NPGC + half * 128 + (wave >> 1) * 64;
    int colbase = blockIdx.y * 128 + (wave & 1) * 64;
    f32x4 zero = {0.f, 0.f, 0.f, 0.f};
    f32x4 acc[4][4];
#pragma unroll
    for (int i = 0; i < 4; ++i)
#pragma unroll
        for (int j = 0; j < 4; ++j) acc[i][j] = zero;
#pragma unroll
    for (int ks = 0; ks < 4; ++ks) {
        int k0 = ks * 32 + quad * 8;
        bf16x8 af[4], bfr[4];
#pragma unroll
        for (int tm = 0; tm < 4; ++tm)
            af[tm] = *(const bf16x8*)(hb + (size_t)(rowbase + tm * 16 + m) * FF + k0);
#pragma unroll
        for (int tn = 0; tn < 4; ++tn)
            bfr[tn] = *(const bf16x8*)(W + (size_t)(colbase + tn * 16 + m) * FF + k0);
#pragma unroll
        for (int tm = 0; tm < 4; ++tm)
#pragma unroll
            for (int tn = 0; tn < 4; ++tn)
                acc[tm][tn] = __builtin_amdgcn_mfma_f32_16x16x32_bf16(af[tm], bfr[tn],
                                                                      acc[tm][tn], 0, 0, 0);
    }
#pragma unroll
    for (int tn = 0; tn < 4; ++tn) {
        int col = colbase + tn * 16 + m;
        float bc = bias[col];
#pragma unroll
        for (int tm = 0; tm < 4; ++tm)
#pragma unroll
            for (int r = 0; r < 4; ++r)
                out[(size_t)(rowbase + tm * 16 + quad * 4 + r) * HDIM + col] =
                    f2b(acc[tm][tn][r] + bc);
    }
}

// ---------------- per-graph per-head S = scale * Q @ K^T via MFMA -------------------
// S layout: [g][h][row_local 256][col_local 256] fp32. All blocks of graph g get
// blockIdx.x ≡ g (mod 8) (XCD locality with producer/consumer kernels).
__global__ __launch_bounds__(256) void k_qk_mfma(const unsigned short* __restrict__ q,
                                                 const unsigned short* __restrict__ kmat,
                                                 float* __restrict__ S) {
    int lane = threadIdx.x & 63, wave = threadIdx.x >> 6;
    int quad = lane >> 4, m = lane & 15;
    int bi = blockIdx.x;  // [0,128)
    int g = (bi & 7) + 8 * ((bi >> 3) & 3);
    int tile = bi >> 5;   // [0,4): (rowtile, coltile)
    int h = blockIdx.y;
    int rowbase = g * NPGC + (tile >> 1) * 128 + (wave >> 1) * 64;
    int colbase = g * NPGC + (tile & 1) * 128 + (wave & 1) * 64;
    f32x4 zero = {0.f, 0.f, 0.f, 0.f};
    f32x4 acc[4][4];
#pragma unroll
    for (int i = 0; i < 4; ++i)
#pragma unroll
        for (int j = 0; j < 4; ++j) acc[i][j] = zero;
#pragma unroll
    for (int ks = 0; ks < 4; ++ks) {
        int k0 = h * DH + ks * 32 + quad * 8;
        bf16x8 af[4], bfr[4];
#pragma unroll
        for (int tm = 0; tm < 4; ++tm)
            af[tm] = *(const bf16x8*)(q + (size_t)(rowbase + tm * 16 + m) * HDIM + k0);
#pragma unroll
        for (int tn = 0; tn < 4; ++tn)
            bfr[tn] = *(const bf16x8*)(kmat + (size_t)(colbase + tn * 16 + m) * HDIM + k0);
#pragma unroll
        for (int tm = 0; tm < 4; ++tm)
#pragma unroll
            for (int tn = 0; tn < 4; ++tn)
                acc[tm][tn] = __builtin_amdgcn_mfma_f32_16x16x32_bf16(af[tm], bfr[tn],
                                                                      acc[tm][tn], 0, 0, 0);
    }
    float* Sg = S + (((size_t)g * NH + h) << 16);
    int rl0 = rowbase - g * NPGC, cl0 = colbase - g * NPGC;
#pragma unroll
    for (int tn = 0; tn < 4; ++tn) {
        int cl = cl0 + tn * 16 + m;
#pragma unroll
        for (int tm = 0; tm < 4; ++tm)
#pragma unroll
            for (int r = 0; r < 4; ++r)
                Sg[(size_t)(rl0 + tm * 16 + quad * 4 + r) * NPGC + cl] =
                    acc[tm][tn][r] * SCALE;
    }
}

// ---------------- output GEMM (h2@Wt) via MFMA + relu + BN epilogue ------------------
__global__ __launch_bounds__(128) void k_out_mfma(
    const unsigned short* __restrict__ h2b, const unsigned short* __restrict__ wt,
    const float* __restrict__ bt_, const float* __restrict__ gam_,
    const float* __restrict__ bet_, const float* __restrict__ rme_,
    const float* __restrict__ rva_, float* __restrict__ hout,
    unsigned short* __restrict__ hbf) {
    int lane = threadIdx.x & 63, wave = threadIdx.x >> 6;
    int quad = lane >> 4, m = lane & 15;
    int bi = blockIdx.x;  // [0,256)
    int g = (bi & 7) + 8 * ((bi >> 3) & 3);
    int sub = bi >> 5;    // [0,8)
    int rowbase = g * NPGC + sub * 32;
    int colbase = wave * 64;
    f32x4 zero = {0.f, 0.f, 0.f, 0.f};
    f32x4 acc[2][4];
#pragma unroll
    for (int i = 0; i < 2; ++i)
#pragma unroll
        for (int j = 0; j < 4; ++j) acc[i][j] = zero;
    for (int ks = 0; ks < 16; ++ks) {
        int k0 = ks * 32 + quad * 8;
        bf16x8 af[2], bfr[4];
#pragma unroll
        for (int tm = 0; tm < 2; ++tm)
            af[tm] = *(const bf16x8*)(h2b + (size_t)(rowbase + tm * 16 + m) * HDIM + k0);
#pragma unroll
        for (int tn = 0; tn < 4; ++tn)
            bfr[tn] = *(const bf16x8*)(wt + (size_t)(colbase + tn * 16 + m) * HDIM + k0);
#pragma unroll
        for (int tm = 0; tm < 2; ++tm)
#pragma unroll
            for (int tn = 0; tn < 4; ++tn)
                acc[tm][tn] = __builtin_amdgcn_mfma_f32_16x16x32_bf16(af[tm], bfr[tn],
                                                                      acc[tm][tn], 0, 0, 0);
    }
#pragma unroll
    for (int tn = 0; tn < 4; ++tn) {
        int col = colbase + tn * 16 + m;
        float bc = bt_[col];
        float sc = gam_[col] * rsqrtf(rva_[col] + 1e-5f);
        float sh = bet_[col] - rme_[col] * sc;
#pragma unroll
        for (int tm = 0; tm < 2; ++tm)
#pragma unroll
            for (int r = 0; r < 4; ++r) {
                size_t o = (size_t)(rowbase + tm * 16 + quad * 4 + r) * FF + col;
                float v = fmaxf(acc[tm][tn][r] + bc, 0.f) * sc + sh;
                hout[o] = v;
                hbf[o] = f2b(v);
            }
    }
}

// ---------------- MLP via MFMA: A[32][K] @ W^T[N][K], split-K partials ---------------
__global__ __launch_bounds__(256) void k_mlp_mfma(const unsigned short* __restrict__ A,
                                                  const unsigned short* __restrict__ Wt,
                                                  float* __restrict__ cp,
                                                  int N, int K, int KS) {
    int lane = threadIdx.x & 63, wave = threadIdx.x >> 6;
    int quad = lane >> 4, m = lane & 15;
    int colbase = blockIdx.x * 256 + wave * 64;
    int kc = K / KS;
    int k0b = blockIdx.y * kc;
    f32x4 zero = {0.f, 0.f, 0.f, 0.f};
    f32x4 acc[2][4];
#pragma unroll
    for (int i = 0; i < 2; ++i)
#pragma unroll
        for (int j = 0; j < 4; ++j) acc[i][j] = zero;
    for (int ks = 0; ks < kc / 32; ++ks) {
        int k0 = k0b + ks * 32 + quad * 8;
        bf16x8 a0 = *(const bf16x8*)(A + (size_t)m * K + k0);
        bf16x8 a1 = *(const bf16x8*)(A + (size_t)(16 + m) * K + k0);
        bf16x8 bfr[4];
#pragma unroll
        for (int tn = 0; tn < 4; ++tn)
            bfr[tn] = *(const bf16x8*)(Wt + (size_t)(colbase + tn * 16 + m) * K + k0);
#pragma unroll
        for (int tn = 0; tn < 4; ++tn) {
            acc[0][tn] = __builtin_amdgcn_mfma_f32_16x16x32_bf16(a0, bfr[tn], acc[0][tn], 0, 0, 0);
            acc[1][tn] = __builtin_amdgcn_mfma_f32_16x16x32_bf16(a1, bfr[tn], acc[1][tn], 0, 0, 0);
        }
    }
#pragma unroll
    for (int tm = 0; tm < 2; ++tm)
#pragma unroll
        for (int tn = 0; tn < 4; ++tn)
#pragma unroll
            for (int r = 0; r < 4; ++r)
                cp[((size_t)blockIdx.y * 32 + tm * 16 + quad * 4 + r) * N +
                   colbase + tn * 16 + m] = acc[tm][tn][r];
}

__global__ void k_mlp_fix(const float* __restrict__ cp, const float* __restrict__ b,
                          float* __restrict__ C, unsigned short* __restrict__ Cb,
                          int MN, int N, int KS, int relu) {
    int i = blockIdx.x * 256 + threadIdx.x;
    if (i >= MN) return;
    float acc = b[i % N];
    for (int s = 0; s < KS; ++s) acc += cp[(size_t)s * MN + i];
    if (relu) acc = fmaxf(acc, 0.f);
    C[i] = acc;
    if (Cb) Cb[i] = f2b(acc);
}

// build g1 = [gmax0+gmax1 | gmean0+gmean1 | esm] in bf16 [32][1536]
__global__ void k_g1(const float* __restrict__ pmax0, const float* __restrict__ psum0,
                     const float* __restrict__ pmax1, const float* __restrict__ psum1,
                     const float* __restrict__ esm, unsigned short* __restrict__ g1b) {
    int i = blockIdx.x * 256 + threadIdx.x;  // 32*1536
    int r = i / 1536, c = i % 1536;
    float v;
    if (c < 128) {
        float m0 = -1e30f, m1 = -1e30f;
#pragma unroll
        for (int q = 0; q < 4; ++q) {
            m0 = fmaxf(m0, pmax0[((size_t)r * 4 + q) * 128 + c]);
            m1 = fmaxf(m1, pmax1[((size_t)r * 4 + q) * 128 + c]);
        }
        v = m0 + m1;
    } else if (c < 256) {
        int d = c - 128;
        float s0 = 0.f, s1 = 0.f;
#pragma unroll
        for (int q = 0; q < 4; ++q) {
            s0 += psum0[((size_t)r * 4 + q) * 128 + d];
            s1 += psum1[((size_t)r * 4 + q) * 128 + d];
        }
        v = s0 * (1.f / 128.f) + s1 * (1.f / 64.f);  // count==kc (unique ranks)
    } else {
        v = esm[(size_t)r * ESMC + c - 256];
    }
    g1b[i] = f2b(v);
}

// ---------------- WAVE-PER-NODE attention: S-table + online softmax, 2-way ILP ------
// q.k scores precomputed by k_qk_mfma (S, scaled). Per edge: broadcast S read +
// eattr + 4 shfls for the qW.ea term + v-row aggregate. No k-row gather.
__global__ __launch_bounds__(256) void k_attn_wave(
    const unsigned short* __restrict__ q, const float* __restrict__ S,
    const unsigned short* __restrict__ vmat, const unsigned short* __restrict__ xr,
    const float* __restrict__ eattr, const float* __restrict__ We,
    const float* __restrict__ Wb,
    const int* __restrict__ src, const int* __restrict__ coff,
    const int* __restrict__ ceid, const int* __restrict__ emask,
    unsigned short* __restrict__ h2) {
    int wv = threadIdx.x >> 6, ln = threadIdx.x & 63;
    int bi = blockIdx.x;  // [0,2048)
    int g = (bi & 7) + 8 * ((bi >> 3) & 3);
    int sub = bi >> 5;    // [0,64)
    int nl = sub * 4 + wv;          // node local id
    int n = g * NPGC + nl;
    int h = ln >> 4, j = ln & 15;
    int d0i = ln * 8;
    int gbase = g * NPGC;
    int o0 = coff[n];
    int deg = coff[n + 1] - o0;
    if (deg > 64) deg = 64;

    uint4 qu = *(const uint4*)(q + (size_t)n * HDIM + d0i);
    float2 q0 = b2f2(qu.x), q1 = b2f2(qu.y), q2 = b2f2(qu.z), q3 = b2f2(qu.w);
    float qf[8] = {q0.x, q0.y, q1.x, q1.y, q2.x, q2.y, q3.x, q3.y};

    // qW in-register (butterfly within 16-lane head groups), pre-scaled
    float qp[16];
#pragma unroll
    for (int jj = 0; jj < EDIMC; ++jj) {
        const float4* wp = (const float4*)(We + (size_t)jj * HDIM + d0i);
        float4 wa = wp[0], wb4 = wp[1];
        qp[jj] = qf[0] * wa.x + qf[1] * wa.y + qf[2] * wa.z + qf[3] * wa.w +
                 qf[4] * wb4.x + qf[5] * wb4.y + qf[6] * wb4.z + qf[7] * wb4.w;
    }
#pragma unroll
    for (int off = 1; off < 16; off <<= 1)
#pragma unroll
        for (int jj = 0; jj < EDIMC; ++jj) qp[jj] += __shfl_xor(qp[jj], off);
    float qWls = qp[j] * SCALE;

    // S row for this (node, head)
    const float* Srow = S + (((size_t)g * NH + h) << 16) + (size_t)nl * NPGC;

    // lane-owned edge
    int e_reg = 0, s_reg = -1;
    if (ln < deg) {
        e_reg = ceid[o0 + ln];
        s_reg = emask[e_reg] ? src[e_reg] : -1;
    }

    // dual online-softmax state
    float mA = -1e30f, denA = 0.f, zA = 0.f;
    float mB = -1e30f, denB = 0.f, zB = 0.f;
    float outA[8] = {0.f, 0.f, 0.f, 0.f, 0.f, 0.f, 0.f, 0.f};
    float outB[8] = {0.f, 0.f, 0.f, 0.f, 0.f, 0.f, 0.f, 0.f};

    int i = 0;
    for (; i + 1 < deg; i += 2) {
        int siA = __shfl(s_reg, i), siB = __shfl(s_reg, i + 1);
        int eiA = __shfl(e_reg, i), eiB = __shfl(e_reg, i + 1);
        int sa = (siA < 0) ? gbase : siA;
        int sb = (siB < 0) ? gbase : siB;
        // loads issued together, branch-free
        float SvA = Srow[sa - gbase];
        float SvB = Srow[sb - gbase];
        uint4 vuA = *(const uint4*)(vmat + (size_t)sa * HDIM + d0i);
        uint4 vuB = *(const uint4*)(vmat + (size_t)sb * HDIM + d0i);
        float eavA = eattr[(size_t)eiA * EDIMC + j];
        float eavB = eattr[(size_t)eiB * EDIMC + j];
        float pA = qWls * eavA;
        float pB = qWls * eavB;
        pA += __shfl_xor(pA, 8);  pB += __shfl_xor(pB, 8);
        pA += __shfl_xor(pA, 4);  pB += __shfl_xor(pB, 4);
        pA += __shfl_xor(pA, 2);  pB += __shfl_xor(pB, 2);
        pA += __shfl_xor(pA, 1);  pB += __shfl_xor(pB, 1);
        float sA = (siA < 0) ? -1e30f : SvA + pA;
        float sB = (siB < 0) ? -1e30f : SvB + pB;
        // state A update
        {
            float m_new = fmaxf(mA, sA);
            float c = __expf(mA - m_new);
            float al = (siA < 0) ? 0.f : __expf(sA - m_new);
            denA = denA * c + al;
            zA = zA * c + al * eavA;
            float2 v0 = b2f2(vuA.x), v1 = b2f2(vuA.y), v2 = b2f2(vuA.z), v3 = b2f2(vuA.w);
            outA[0] = outA[0] * c + al * v0.x;
            outA[1] = outA[1] * c + al * v0.y;
            outA[2] = outA[2] * c + al * v1.x;
            outA[3] = outA[3] * c + al * v1.y;
            outA[4] = outA[4] * c + al * v2.x;
            outA[5] = outA[5] * c + al * v2.y;
            outA[6] = outA[6] * c + al * v3.x;
            outA[7] = outA[7] * c + al * v3.y;
            mA = m_new;
        }
        // state B update (independent)
        {
            float m_new = fmaxf(mB, sB);
            float c = __expf(mB - m_new);
            float al = (siB < 0) ? 0.f : __expf(sB - m_new);
            denB = denB * c + al;
            zB = zB * c + al * eavB;
            float2 v0 = b2f2(vuB.x), v1 = b2f2(vuB.y), v2 = b2f2(vuB.z), v3 = b2f2(vuB.w);
            outB[0] = outB[0] * c + al * v0.x;
            outB[1] = outB[1] * c + al * v0.y;
            outB[2] = outB[2] * c + al * v1.x;
            outB[3] = outB[3] * c + al * v1.y;
            outB[4] = outB[4] * c + al * v2.x;
            outB[5] = outB[5] * c + al * v2.y;
            outB[6] = outB[6] * c + al * v3.x;
            outB[7] = outB[7] * c + al * v3.y;
            mB = m_new;
        }
    }
    if (i < deg) {  // tail edge -> state A
        int siA = __shfl(s_reg, i);
        int eiA = __shfl(e_reg, i);
        int sa = (siA < 0) ? gbase : siA;
        float SvA = Srow[sa - gbase];
        uint4 vuA = *(const uint4*)(vmat + (size_t)sa * HDIM + d0i);
        float eavA = eattr[(size_t)eiA * EDIMC + j];
        float pA = qWls * eavA;
        pA += __shfl_xor(pA, 8);
        pA += __shfl_xor(pA, 4);
        pA += __shfl_xor(pA, 2);
        pA += __shfl_xor(pA, 1);
        float sA = (siA < 0) ? -1e30f : SvA + pA;
        float m_new = fmaxf(mA, sA);
        float c = __expf(mA - m_new);
        float al = (siA < 0) ? 0.f : __expf(sA - m_new);
        denA = denA * c + al;
        zA = zA * c + al * eavA;
        float2 v0 = b2f2(vuA.x), v1 = b2f2(vuA.y), v2 = b2f2(vuA.z), v3 = b2f2(vuA.w);
        outA[0] = outA[0] * c + al * v0.x;
        outA[1] = outA[1] * c + al * v0.y;
        outA[2] = outA[2] * c + al * v1.x;
        outA[3] = outA[3] * c + al * v1.y;
        outA[4] = outA[4] * c + al * v2.x;
        outA[5] = outA[5] * c + al * v2.y;
        outA[6] = outA[6] * c + al * v3.x;
        outA[7] = outA[7] * c + al * v3.y;
        mA = m_new;
    }
    // exact merge of the two states
    float mT = fmaxf(mA, mB);
    float cA = __expf(mA - mT), cB = __expf(mB - mT);
    float den = denA * cA + denB * cB;
    float z = zA * cA + zB * cB;
    float out[8];
#pragma unroll
    for (int d = 0; d < 8; ++d) out[d] = outA[d] * cA + outB[d] * cB;

    float inv = 1.f / fmaxf(den, 1e-16f);
    z *= inv;
#pragma unroll
    for (int d = 0; d < 8; ++d) out[d] *= inv;

    // eproj
#pragma unroll
    for (int jj = 0; jj < EDIMC; ++jj) {
        float zjj = __shfl(z, h * 16 + jj);
        const float4* wp = (const float4*)(We + (size_t)jj * HDIM + d0i);
        float4 wa = wp[0], wb4 = wp[1];
        out[0] = fmaf(zjj, wa.x, out[0]);
        out[1] = fmaf(zjj, wa.y, out[1]);
        out[2] = fmaf(zjj, wa.z, out[2]);
        out[3] = fmaf(zjj, wa.w, out[3]);
        out[4] = fmaf(zjj, wb4.x, out[4]);
        out[5] = fmaf(zjj, wb4.y, out[5]);
        out[6] = fmaf(zjj, wb4.z, out[6]);
        out[7] = fmaf(zjj, wb4.w, out[7]);
    }

    // beta gate + gated combine
    uint4 xu = *(const uint4*)(xr + (size_t)n * HDIM + d0i);
    float2 x0 = b2f2(xu.x), x1 = b2f2(xu.y), x2 = b2f2(xu.z), x3 = b2f2(xu.w);
    float xf[8] = {x0.x, x0.y, x1.x, x1.y, x2.x, x2.y, x3.x, x3.y};
    const float4* w0p = (const float4*)(Wb + d0i);
    const float4* w1p = (const float4*)(Wb + HDIM + d0i);
    const float4* w2p = (const float4*)(Wb + 2 * HDIM + d0i);
    float4 wa0 = w0p[0], wa1 = w0p[1];
    float4 wb0 = w1p[0], wb1 = w1p[1];
    float4 wc0 = w2p[0], wc1 = w2p[1];
    float w0f[8] = {wa0.x, wa0.y, wa0.z, wa0.w, wa1.x, wa1.y, wa1.z, wa1.w};
    float w1f[8] = {wb0.x, wb0.y, wb0.z, wb0.w, wb1.x, wb1.y, wb1.z, wb1.w};
    float w2f[8] = {wc0.x, wc0.y, wc0.z, wc0.w, wc1.x, wc1.y, wc1.z, wc1.w};
    float part = 0.f;
#pragma unroll
    for (int d = 0; d < 8; ++d)
        part += out[d] * w0f[d] + xf[d] * w1f[d] + (out[d] - xf[d]) * w2f[d];
#pragma unroll
    for (int o = 32; o > 0; o >>= 1) part += __shfl_xor(part, o);
    float bg = 1.f / (1.f + __expf(-part));
    uint4 res;
    res.x = pack2(bg * xf[0] + (1.f - bg) * out[0], bg * xf[1] + (1.f - bg) * out[1]);
    res.y = pack2(bg * xf[2] + (1.f - bg) * out[2], bg * xf[3] + (1.f - bg) * out[3]);
    res.z = pack2(bg * xf[4] + (1.f - bg) * out[4], bg * xf[5] + (1.f - bg) * out[5]);
    res.w = pack2(bg * xf[6] + (1.f - bg) * out[6], bg * xf[7] + (1.f - bg) * out[7]);
    *(uint4*)(h2 + (size_t)n * HDIM + d0i) = res;
}

// ---------------- TopK pool, split for parallelism ----------------------------------
__global__ __launch_bounds__(256) void k_pool_rank(const float* __restrict__ pwv,
                                                   const float* __restrict__ h,
                                                   int* __restrict__ nmask,
                                                   int* __restrict__ emask,  // null => skip
                                                   const int* __restrict__ src,
                                                   const int* __restrict__ dst,
                                                   float* __restrict__ fbuf, int kc) {
    __shared__ float smS[NPGC];
    __shared__ int keepS[NPGC];
    int g = blockIdx.x, t = threadIdx.x;
    int n = g * NPGC + t;
    const float* hr = h + (size_t)n * FF;
    float nw2 = 0.f, dv = 0.f;
#pragma unroll
    for (int i = 0; i < FF; i += 4) {
        float4 wv = *(const float4*)(pwv + i);
        float4 hv = *(const float4*)(hr + i);
        nw2 += wv.x * wv.x + wv.y * wv.y + wv.z * wv.z + wv.w * wv.w;
        dv += hv.x * wv.x + hv.y * wv.y + hv.z * wv.z + hv.w * wv.w;
    }
    float s = tanhf(dv / sqrtf(nw2));
    int old = nmask[n];
    smS[t] = old ? s : -INFINITY;
    __syncthreads();
    float mys = smS[t];
    int rank = 0;
    for (int j = 0; j < NPGC; ++j) {
        float o = smS[j];
        rank += (o > mys) || (o == mys && j < t);  // stable argsort tie-break
    }
    int kp = (rank < kc) && old;  // ranks unique -> exactly kc kept per graph
    keepS[t] = kp;
    nmask[n] = kp;
    fbuf[n] = s * (float)kp;
    __syncthreads();
    if (emask) {
        int base = g * EGC;
        for (int ee = t; ee < EGC; ee += 256) {
            int e = base + ee;
            emask[e] = emask[e] && keepS[src[e] - g * NPGC] && keepS[dst[e] - g * NPGC];
        }
    }
}

// apply: grid (BB,4): scale, optional bf16 emit, per-dim max/sum partials (64 nodes).
__global__ __launch_bounds__(256) void k_pool_apply(const float* __restrict__ h,
                                                    unsigned short* __restrict__ hbf,
                                                    const float* __restrict__ fbuf,
                                                    const int* __restrict__ nmask,
                                                    float* __restrict__ pmax,
                                                    float* __restrict__ psum, int emit) {
    __shared__ float mS[4][128];
    __shared__ float sS[4][128];
    int g = blockIdx.x, seg = blockIdx.y, t = threadIdx.x;
    int l = t & 63, quar = t >> 6;
    int d2 = l * 2;
    int nbase = g * NPGC + seg * 64 + quar * 16;
    float mx0 = -1e30f, mx1 = -1e30f, sm0 = 0.f, sm1 = 0.f;
#pragma unroll 4
    for (int i = 0; i < 16; ++i) {
        int n = nbase + i;
        float f = fbuf[n];
        int kp = nmask[n];
        float2 hv = *(const float2*)(h + (size_t)n * FF + d2);
        float v0 = hv.x * f, v1 = hv.y * f;
        if (emit) *(unsigned*)(hbf + (size_t)n * FF + d2) = pack2(v0, v1);
        if (kp) {
            mx0 = fmaxf(mx0, v0);
            mx1 = fmaxf(mx1, v1);
            sm0 += v0;
            sm1 += v1;
        }
    }
    mS[quar][d2] = mx0;
    mS[quar][d2 + 1] = mx1;
    sS[quar][d2] = sm0;
    sS[quar][d2 + 1] = sm1;
    __syncthreads();
    if (t < 128) {
        float m = fmaxf(fmaxf(mS[0][t], mS[1][t]), fmaxf(mS[2][t], mS[3][t]));
        float s = sS[0][t] + sS[1][t] + sS[2][t] + sS[3][t];
        pmax[((size_t)g * 4 + seg) * 128 + t] = m;
        psum[((size_t)g * 4 + seg) * 128 + t] = s;
    }
}

// final 32x10 layer (fp32, tiny)
__global__ __launch_bounds__(256) void k_mlp_wave(const float* __restrict__ A,
                                                  const float* __restrict__ W,
                                                  const float* __restrict__ b,
                                                  float* __restrict__ C,
                                                  int M, int N, int K, int relu) {
    int wid = (blockIdx.x * 256 + threadIdx.x) >> 6;
    int lane = threadIdx.x & 63;
    if (wid >= M * N) return;
    int r = wid / N, c = wid % N;
    const float* Arow = A + (size_t)r * K;
    float acc = 0.f;
    for (int kk = lane; kk < K; kk += 64)
        acc = fmaf(Arow[kk], W[(size_t)kk * N + c], acc);
    acc = waveReduceSum(acc);
    if (lane == 0) {
        acc += b[c];
        C[wid] = relu ? fmaxf(acc, 0.f) : acc;
    }
}

// ---------------- host launch ----------------
extern "C" void kernel_launch(void* const* d_in, const int* in_sizes, int n_in,
                              void* d_out, int out_size, void* d_ws, size_t ws_size,
                              hipStream_t stream) {
    const float* x = (const float*)d_in[0];
    const float* eattr = (const float*)d_in[1];
    const int* eidx = (const int*)d_in[2];
    const float* esm = (const float*)d_in[4];
    const float* Wq = (const float*)d_in[5];
    const float* bq = (const float*)d_in[6];
    const float* Wk = (const float*)d_in[7];
    const float* bk = (const float*)d_in[8];
    const float* Wv = (const float*)d_in[9];
    const float* bv = (const float*)d_in[10];
    const float* We = (const float*)d_in[11];
    const float* Wsk = (const float*)d_in[12];
    const float* bsk = (const float*)d_in[13];
    const float* Wbe = (const float*)d_in[14];
    const float* Wt = (const float*)d_in[15];
    const float* bt = (const float*)d_in[16];
    const float* gam = (const float*)d_in[17];
    const float* bet = (const float*)d_in[18];
    const float* rme = (const float*)d_in[19];
    const float* rva = (const float*)d_in[20];
    const float* pw = (const float*)d_in[21];
    const float* W1 = (const float*)d_in[22];
    const float* b1 = (const float*)d_in[23];
    const float* W2 = (const float*)d_in[24];
    const float* b2 = (const float*)d_in[25];
    const float* W3 = (const float*)d_in[26];
    const float* b3 = (const float*)d_in[27];
    const int* srcp = eidx;
    const int* dstp = eidx + NEDGE;

    char* p = (char*)d_ws;
    auto alloc = [&](size_t bytes) -> void* {
        void* r = (void*)p;
        p += (bytes + 255) & ~(size_t)255;
        return r;
    };
    float* hA = (float*)alloc((size_t)NNODE * FF * 4);
    float* hB = (float*)alloc((size_t)NNODE * FF * 4);
    float* Sbuf = (float*)alloc((size_t)BB * NH * NPGC * NPGC * 4);  // 33.5 MB
    float* fbuf = (float*)alloc((size_t)NNODE * 4);
    float* pmax0 = (float*)alloc((size_t)BB * 4 * 128 * 4);
    float* psum0 = (float*)alloc((size_t)BB * 4 * 128 * 4);
    float* pmax1 = (float*)alloc((size_t)BB * 4 * 128 * 4);
    float* psum1 = (float*)alloc((size_t)BB * 4 * 128 * 4);
    float* g2 = (float*)alloc((size_t)BB * 512 * 4);
    float* g3 = (float*)alloc((size_t)BB * 256 * 4);
    float* cp = (float*)alloc((size_t)8 * 32 * 512 * 4);
    int* nmask = (int*)alloc((size_t)NNODE * 4);
    int* emask = (int*)alloc((size_t)NEDGE * 4);
    int* coff = (int*)alloc((size_t)(NNODE + 1) * 4);
    int* ceid = (int*)alloc((size_t)NEDGE * 4);
    // bf16 buffers
    unsigned short* xb = (unsigned short*)alloc((size_t)NNODE * FF * 2);
    unsigned short* hbf = (unsigned short*)alloc((size_t)NNODE * FF * 2);
    unsigned short* qb16 = (unsigned short*)alloc((size_t)NNODE * HDIM * 2);
    unsigned short* kb16 = (unsigned short*)alloc((size_t)NNODE * HDIM * 2);
    unsigned short* vb16 = (unsigned short*)alloc((size_t)NNODE * HDIM * 2);
    unsigned short* xrb16 = (unsigned short*)alloc((size_t)NNODE * HDIM * 2);
    unsigned short* h2b16 = (unsigned short*)alloc((size_t)NNODE * HDIM * 2);
    unsigned short* wqb = (unsigned short*)alloc((size_t)4 * 65536 * 2);
    unsigned short* wkb = (unsigned short*)alloc((size_t)4 * 65536 * 2);
    unsigned short* wvb = (unsigned short*)alloc((size_t)4 * 65536 * 2);
    unsigned short* wskb = (unsigned short*)alloc((size_t)4 * 65536 * 2);
    unsigned short* wtb = (unsigned short*)alloc((size_t)4 * 65536 * 2);
    unsigned short* w1b = (unsigned short*)alloc((size_t)786432 * 2);
    unsigned short* w2b = (unsigned short*)alloc((size_t)131072 * 2);
    unsigned short* g1b = (unsigned short*)alloc((size_t)BB * 1536 * 2);
    unsigned short* g2b = (unsigned short*)alloc((size_t)BB * 512 * 2);

    k_convert_setup<<<12832, 256, 0, stream>>>(x, Wq, Wk, Wv, Wsk, Wt, W1, W2,
                                               xb, wqb, wkb, wvb, wskb, wtb, w1b, w2b,
                                               dstp, emask, nmask, coff, ceid);

    auto conv = [&](int li, const unsigned short* hin_b, float* hout) {
        dim3 gq(64, 4, 4);
        k_qkvs_mfma<<<gq, 256, 0, stream>>>(
            hin_b, wqb + (size_t)li * 65536, wkb + (size_t)li * 65536,
            wvb + (size_t)li * 65536, wskb + (size_t)li * 65536,
            bq + li * HDIM, bk + li * HDIM, bv + li * HDIM, bsk + li * HDIM,
            qb16, kb16, vb16, xrb16);
        k_qk_mfma<<<dim3(128, 4), 256, 0, stream>>>(qb16, kb16, Sbuf);
        const float* WeL = We + (size_t)li * EDIMC * HDIM;
        k_attn_wave<<<NNODE / 4, 256, 0, stream>>>(qb16, Sbuf, vb16, xrb16, eattr, WeL,
                                                   Wbe + (size_t)li * 3 * HDIM,
                                                   srcp, coff, ceid, emask, h2b16);
        k_out_mfma<<<NNODE / 32, 128, 0, stream>>>(
            h2b16, wtb + (size_t)li * 65536, bt + li * FF, gam + li * FF,
            bet + li * FF, rme + li * FF, rva + li * FF, hout, hbf);
    };

    auto pool = [&](int pi, const float* h, float* pmax, float* psum, int kc, bool updE,
                    int emit) {
        k_pool_rank<<<BB, 256, 0, stream>>>(pw + pi * FF, h, nmask,
                                            updE ? emask : nullptr, srcp, dstp, fbuf, kc);
        k_pool_apply<<<dim3(BB, 4), 256, 0, stream>>>(h, hbf, fbuf, nmask, pmax, psum, emit);
    };

    // layer 4 of the reference is dead code (output feeds nothing) — skipped.
    conv(0, xb, hA);
    conv(1, hbf, hB);
    pool(0, hB, pmax0, psum0, NPGC / 2, true, 1);   // emits bf16 h for conv2
    conv(2, hbf, hA);
    conv(3, hbf, hB);
    pool(1, hB, pmax1, psum1, NPGC / 4, false, 0);  // nothing downstream reads h

    k_g1<<<BB * 1536 / 256, 256, 0, stream>>>(pmax0, psum0, pmax1, psum1, esm, g1b);
    k_mlp_mfma<<<dim3(2, 8), 256, 0, stream>>>(g1b, w1b, cp, 512, 1536, 8);
    k_mlp_fix<<<BB * 512 / 256, 256, 0, stream>>>(cp, b1, g2, g2b, BB * 512, 512, 8, 1);
    k_mlp_mfma<<<dim3(1, 8), 256, 0, stream>>>(g2b, w2b, cp, 256, 512, 8);
    k_mlp_fix<<<BB * 256 / 256, 256, 0, stream>>>(cp, b2, g3, nullptr, BB * 256, 256, 8, 1);
    k_mlp_wave<<<(BB * 10 * 64 + 255) / 256, 256, 0, stream>>>(g3, W3, b3, (float*)d_out,
                                                               BB, 10, 256, 0);
}

// Round 15
// 491.126 us; speedup vs baseline: 1.0325x; 1.0325x over previous
//
#include <hip/hip_runtime.h>
#include <math.h>

#define BB 32
#define NPGC 256
#define FF 128
#define EDIMC 16
#define ESMC 1280
#define NNODE 8192
#define NEDGE 65536
#define EGC 2048
#define NH 4
#define DH 128
#define HDIM 512
#define SCALE 0.088388347648318447f  // 1/sqrt(128)

typedef __attribute__((ext_vector_type(8))) short bf16x8;
typedef __attribute__((ext_vector_type(4))) float f32x4;

__device__ __forceinline__ float waveReduceSum(float v) {
#pragma unroll
    for (int o = 32; o > 0; o >>= 1) v += __shfl_down(v, o);
    return v;
}

// fp32 -> bf16 (RNE), raw ushort
__device__ __forceinline__ unsigned short f2b(float f) {
    unsigned u = __builtin_bit_cast(unsigned, f);
    return (unsigned short)((u + 0x7fffu + ((u >> 16) & 1u)) >> 16);
}
__device__ __forceinline__ unsigned pack2(float lo, float hi) {
    return (unsigned)f2b(lo) | ((unsigned)f2b(hi) << 16);
}
// packed pair of bf16 (as uint) -> two floats
__device__ __forceinline__ float2 b2f2(unsigned u) {
    float lo = __builtin_bit_cast(float, u << 16);
    float hi = __builtin_bit_cast(float, u & 0xffff0000u);
    return make_float2(lo, hi);
}

// ---------------- FUSED convert + setup -------------------------------------------
__global__ __launch_bounds__(256) void k_convert_setup(
    const float* __restrict__ x, const float* __restrict__ Wq,
    const float* __restrict__ Wk, const float* __restrict__ Wv,
    const float* __restrict__ Wsk, const float* __restrict__ Wt,
    const float* __restrict__ W1, const float* __restrict__ W2,
    unsigned short* __restrict__ xb, unsigned short* __restrict__ wqb,
    unsigned short* __restrict__ wkb, unsigned short* __restrict__ wvb,
    unsigned short* __restrict__ wskb, unsigned short* __restrict__ wtb,
    unsigned short* __restrict__ w1b, unsigned short* __restrict__ w2b,
    const int* __restrict__ dst, int* __restrict__ emask, int* __restrict__ nmask,
    int* __restrict__ coff, int* __restrict__ ceid) {
    __shared__ int cntS[NPGC];
    __shared__ int scanS[NPGC];
    __shared__ int offS[NPGC];
    if (blockIdx.x >= 12800) {
        int g = blockIdx.x - 12800, t = threadIdx.x;
        cntS[t] = 0;
        nmask[g * NPGC + t] = 1;
        __syncthreads();
        int base = g * EGC;
#pragma unroll
        for (int i = 0; i < EGC / 256; ++i) {
            int e = base + i * 256 + t;
            emask[e] = 1;
            atomicAdd(&cntS[dst[e] - g * NPGC], 1);
        }
        __syncthreads();
        scanS[t] = cntS[t];
        __syncthreads();
        for (int off = 1; off < NPGC; off <<= 1) {
            int v = scanS[t];
            if (t >= off) v += scanS[t - off];
            __syncthreads();
            scanS[t] = v;
            __syncthreads();
        }
        int excl = scanS[t] - cntS[t];
        offS[t] = excl;
        coff[g * NPGC + t] = base + excl;
        if (g == 0 && t == 0) coff[NNODE] = NEDGE;
        cntS[t] = 0;
        __syncthreads();
#pragma unroll
        for (int i = 0; i < EGC / 256; ++i) {
            int e = base + i * 256 + t;
            int d = dst[e] - g * NPGC;
            int pos = atomicAdd(&cntS[d], 1);
            ceid[base + offS[d] + pos] = e;
        }
        return;
    }
    int idx = blockIdx.x * 256 + threadIdx.x;
    if (idx < 1048576) { xb[idx] = f2b(x[idx]); return; }
    idx -= 1048576;
    if (idx < 1048576) {  // Wq/Wk/Wv/Wskip: [li][128][512] -> [li][512][128]
        int fam = idx >> 18, local = idx & 262143;
        int li = local >> 16, rem = local & 65535;
        int n = rem >> 7, k = rem & 127;
        const float* S = (fam == 0) ? Wq : (fam == 1) ? Wk : (fam == 2) ? Wv : Wsk;
        unsigned short* D = (fam == 0) ? wqb : (fam == 1) ? wkb : (fam == 2) ? wvb : wskb;
        D[local] = f2b(S[(size_t)li * 65536 + (size_t)k * 512 + n]);
        return;
    }
    idx -= 1048576;
    if (idx < 262144) {  // Wt: [li][512][128] -> [li][128][512]
        int li = idx >> 16, rem = idx & 65535;
        int n = rem >> 9, k = rem & 511;
        wtb[idx] = f2b(Wt[(size_t)li * 65536 + (size_t)k * 128 + n]);
        return;
    }
    idx -= 262144;
    if (idx < 786432) {  // W1: [1536][512] -> [512][1536]
        int n = idx / 1536, k = idx % 1536;
        w1b[idx] = f2b(W1[(size_t)k * 512 + n]);
        return;
    }
    idx -= 786432;
    {  // W2: [512][256] -> [256][512]
        int n = idx >> 9, k = idx & 511;
        w2b[idx] = f2b(W2[(size_t)k * 256 + n]);
    }
}

// ---------------- fused q/k/v/skip GEMM via MFMA bf16 -> bf16 outputs ----------------
__global__ __launch_bounds__(256) void k_qkvs_mfma(
    const unsigned short* __restrict__ hb,
    const unsigned short* __restrict__ wq, const unsigned short* __restrict__ wk,
    const unsigned short* __restrict__ wv, const unsigned short* __restrict__ wsk,
    const float* __restrict__ bq, const float* __restrict__ bk,
    const float* __restrict__ bv, const float* __restrict__ bsk,
    unsigned short* __restrict__ oq, unsigned short* __restrict__ ok,
    unsigned short* __restrict__ ov, unsigned short* __restrict__ osk) {
    const unsigned short* W;
    const float* bias;
    unsigned short* out;
    if (blockIdx.z == 0) { W = wq; bias = bq; out = oq; }
    else if (blockIdx.z == 1) { W = wk; bias = bk; out = ok; }
    else if (blockIdx.z == 2) { W = wv; bias = bv; out = ov; }
    else { W = wsk; bias = bsk; out = osk; }
    int lane = threadIdx.x & 63, wave = threadIdx.x >> 6;
    int quad = lane >> 4, m = lane & 15;
    int xcdx = blockIdx.x;  // [0,64): graph g = (bi&7)+8*((bi>>3)&3), half = bi>>5
    int g = (xcdx & 7) + 8 * ((xcdx >> 3) & 3);
    int half = xcdx >> 5;
    int rowbase = g * NPGC + half * 128 + (wave >> 1) * 64;
    int colbase = blockIdx.y * 128 + (wave & 1) * 64;
    f32x4 zero = {0.f, 0.f, 0.f, 0.f};
    f32x4 acc[4][4];
#pragma unroll
    for (int i = 0; i < 4; ++i)
#pragma unroll
        for (int j = 0; j < 4; ++j) acc[i][j] = zero;
#pragma unroll
    for (int ks = 0; ks < 4; ++ks) {
        int k0 = ks * 32 + quad * 8;
        bf16x8 af[4], bfr[4];
#pragma unroll
        for (int tm = 0; tm < 4; ++tm)
            af[tm] = *(const bf16x8*)(hb + (size_t)(rowbase + tm * 16 + m) * FF + k0);
#pragma unroll
        for (int tn = 0; tn < 4; ++tn)
            bfr[tn] = *(const bf16x8*)(W + (size_t)(colbase + tn * 16 + m) * FF + k0);
#pragma unroll
        for (int tm = 0; tm < 4; ++tm)
#pragma unroll
            for (int tn = 0; tn < 4; ++tn)
                acc[tm][tn] = __builtin_amdgcn_mfma_f32_16x16x32_bf16(af[tm], bfr[tn],
                                                                      acc[tm][tn], 0, 0, 0);
    }
#pragma unroll
    for (int tn = 0; tn < 4; ++tn) {
        int col = colbase + tn * 16 + m;
        float bc = bias[col];
#pragma unroll
        for (int tm = 0; tm < 4; ++tm)
#pragma unroll
            for (int r = 0; r < 4; ++r)
                out[(size_t)(rowbase + tm * 16 + quad * 4 + r) * HDIM + col] =
                    f2b(acc[tm][tn][r] + bc);
    }
}

// ---------------- output GEMM (h2@Wt) via MFMA + relu + BN epilogue ------------------
__global__ __launch_bounds__(128) void k_out_mfma(
    const unsigned short* __restrict__ h2b, const unsigned short* __restrict__ wt,
    const float* __restrict__ bt_, const float* __restrict__ gam_,
    const float* __restrict__ bet_, const float* __restrict__ rme_,
    const float* __restrict__ rva_, float* __restrict__ hout,
    unsigned short* __restrict__ hbf) {
    int lane = threadIdx.x & 63, wave = threadIdx.x >> 6;
    int quad = lane >> 4, m = lane & 15;
    int bi = blockIdx.x;  // [0,256)
    int g = (bi & 7) + 8 * ((bi >> 3) & 3);
    int sub = bi >> 5;    // [0,8)
    int rowbase = g * NPGC + sub * 32;
    int colbase = wave * 64;
    f32x4 zero = {0.f, 0.f, 0.f, 0.f};
    f32x4 acc[2][4];
#pragma unroll
    for (int i = 0; i < 2; ++i)
#pragma unroll
        for (int j = 0; j < 4; ++j) acc[i][j] = zero;
    for (int ks = 0; ks < 16; ++ks) {
        int k0 = ks * 32 + quad * 8;
        bf16x8 af[2], bfr[4];
#pragma unroll
        for (int tm = 0; tm < 2; ++tm)
            af[tm] = *(const bf16x8*)(h2b + (size_t)(rowbase + tm * 16 + m) * HDIM + k0);
#pragma unroll
        for (int tn = 0; tn < 4; ++tn)
            bfr[tn] = *(const bf16x8*)(wt + (size_t)(colbase + tn * 16 + m) * HDIM + k0);
#pragma unroll
        for (int tm = 0; tm < 2; ++tm)
#pragma unroll
            for (int tn = 0; tn < 4; ++tn)
                acc[tm][tn] = __builtin_amdgcn_mfma_f32_16x16x32_bf16(af[tm], bfr[tn],
                                                                      acc[tm][tn], 0, 0, 0);
    }
#pragma unroll
    for (int tn = 0; tn < 4; ++tn) {
        int col = colbase + tn * 16 + m;
        float bc = bt_[col];
        float sc = gam_[col] * rsqrtf(rva_[col] + 1e-5f);
        float sh = bet_[col] - rme_[col] * sc;
#pragma unroll
        for (int tm = 0; tm < 2; ++tm)
#pragma unroll
            for (int r = 0; r < 4; ++r) {
                size_t o = (size_t)(rowbase + tm * 16 + quad * 4 + r) * FF + col;
                float v = fmaxf(acc[tm][tn][r] + bc, 0.f) * sc + sh;
                hout[o] = v;
                hbf[o] = f2b(v);
            }
    }
}

// ---------------- MLP via MFMA: A[32][K] @ W^T[N][K], split-K partials ---------------
__global__ __launch_bounds__(256) void k_mlp_mfma(const unsigned short* __restrict__ A,
                                                  const unsigned short* __restrict__ Wt,
                                                  float* __restrict__ cp,
                                                  int N, int K, int KS) {
    int lane = threadIdx.x & 63, wave = threadIdx.x >> 6;
    int quad = lane >> 4, m = lane & 15;
    int colbase = blockIdx.x * 256 + wave * 64;
    int kc = K / KS;
    int k0b = blockIdx.y * kc;
    f32x4 zero = {0.f, 0.f, 0.f, 0.f};
    f32x4 acc[2][4];
#pragma unroll
    for (int i = 0; i < 2; ++i)
#pragma unroll
        for (int j = 0; j < 4; ++j) acc[i][j] = zero;
    for (int ks = 0; ks < kc / 32; ++ks) {
        int k0 = k0b + ks * 32 + quad * 8;
        bf16x8 a0 = *(const bf16x8*)(A + (size_t)m * K + k0);
        bf16x8 a1 = *(const bf16x8*)(A + (size_t)(16 + m) * K + k0);
        bf16x8 bfr[4];
#pragma unroll
        for (int tn = 0; tn < 4; ++tn)
            bfr[tn] = *(const bf16x8*)(Wt + (size_t)(colbase + tn * 16 + m) * K + k0);
#pragma unroll
        for (int tn = 0; tn < 4; ++tn) {
            acc[0][tn] = __builtin_amdgcn_mfma_f32_16x16x32_bf16(a0, bfr[tn], acc[0][tn], 0, 0, 0);
            acc[1][tn] = __builtin_amdgcn_mfma_f32_16x16x32_bf16(a1, bfr[tn], acc[1][tn], 0, 0, 0);
        }
    }
#pragma unroll
    for (int tm = 0; tm < 2; ++tm)
#pragma unroll
        for (int tn = 0; tn < 4; ++tn)
#pragma unroll
            for (int r = 0; r < 4; ++r)
                cp[((size_t)blockIdx.y * 32 + tm * 16 + quad * 4 + r) * N +
                   colbase + tn * 16 + m] = acc[tm][tn][r];
}

__global__ void k_mlp_fix(const float* __restrict__ cp, const float* __restrict__ b,
                          float* __restrict__ C, unsigned short* __restrict__ Cb,
                          int MN, int N, int KS, int relu) {
    int i = blockIdx.x * 256 + threadIdx.x;
    if (i >= MN) return;
    float acc = b[i % N];
    for (int s = 0; s < KS; ++s) acc += cp[(size_t)s * MN + i];
    if (relu) acc = fmaxf(acc, 0.f);
    C[i] = acc;
    if (Cb) Cb[i] = f2b(acc);
}

// build g1 = [gmax0+gmax1 | gmean0+gmean1 | esm] in bf16 [32][1536]
__global__ void k_g1(const float* __restrict__ pmax0, const float* __restrict__ psum0,
                     const float* __restrict__ pmax1, const float* __restrict__ psum1,
                     const float* __restrict__ esm, unsigned short* __restrict__ g1b) {
    int i = blockIdx.x * 256 + threadIdx.x;  // 32*1536
    int r = i / 1536, c = i % 1536;
    float v;
    if (c < 128) {
        float m0 = -1e30f, m1 = -1e30f;
#pragma unroll
        for (int q = 0; q < 4; ++q) {
            m0 = fmaxf(m0, pmax0[((size_t)r * 4 + q) * 128 + c]);
            m1 = fmaxf(m1, pmax1[((size_t)r * 4 + q) * 128 + c]);
        }
        v = m0 + m1;
    } else if (c < 256) {
        int d = c - 128;
        float s0 = 0.f, s1 = 0.f;
#pragma unroll
        for (int q = 0; q < 4; ++q) {
            s0 += psum0[((size_t)r * 4 + q) * 128 + d];
            s1 += psum1[((size_t)r * 4 + q) * 128 + d];
        }
        v = s0 * (1.f / 128.f) + s1 * (1.f / 64.f);  // count==kc (unique ranks)
    } else {
        v = esm[(size_t)r * ESMC + c - 256];
    }
    g1b[i] = f2b(v);
}

// ---------------- WAVE-PER-NODE attention: online softmax, 4-way ILP, branch-free ---
// Round-13 structure (k-row gather + online softmax) with FOUR independent
// states: loads for 4 edges batched up front, 4 interleaved score reductions,
// 4 independent rescale chains, exact 4-way merge at the end.
__global__ __launch_bounds__(256) void k_attn_wave(
    const unsigned short* __restrict__ q, const unsigned short* __restrict__ kmat,
    const unsigned short* __restrict__ vmat, const unsigned short* __restrict__ xr,
    const float* __restrict__ eattr, const float* __restrict__ We,
    const float* __restrict__ Wb,
    const int* __restrict__ src, const int* __restrict__ coff,
    const int* __restrict__ ceid, const int* __restrict__ emask,
    unsigned short* __restrict__ h2) {
    int wv = threadIdx.x >> 6, ln = threadIdx.x & 63;
    int bi = blockIdx.x;  // [0,2048)
    int g = (bi & 7) + 8 * ((bi >> 3) & 3);
    int sub = bi >> 5;    // [0,64)
    int n = g * NPGC + sub * 4 + wv;
    int h = ln >> 4, j = ln & 15;
    int d0i = ln * 8;
    int o0 = coff[n];
    int deg = coff[n + 1] - o0;
    if (deg > 64) deg = 64;

    uint4 qu = *(const uint4*)(q + (size_t)n * HDIM + d0i);
    float2 q0 = b2f2(qu.x), q1 = b2f2(qu.y), q2 = b2f2(qu.z), q3 = b2f2(qu.w);
    float qf[8] = {q0.x, q0.y, q1.x, q1.y, q2.x, q2.y, q3.x, q3.y};

    // qW in-register (butterfly within 16-lane head groups)
    float qp[16];
#pragma unroll
    for (int jj = 0; jj < EDIMC; ++jj) {
        const float4* wp = (const float4*)(We + (size_t)jj * HDIM + d0i);
        float4 wa = wp[0], wb4 = wp[1];
        qp[jj] = qf[0] * wa.x + qf[1] * wa.y + qf[2] * wa.z + qf[3] * wa.w +
                 qf[4] * wb4.x + qf[5] * wb4.y + qf[6] * wb4.z + qf[7] * wb4.w;
    }
#pragma unroll
    for (int off = 1; off < 16; off <<= 1)
#pragma unroll
        for (int jj = 0; jj < EDIMC; ++jj) qp[jj] += __shfl_xor(qp[jj], off);
    float qWl = qp[j];

    // lane-owned edge
    int e_reg = 0, s_reg = -1;
    if (ln < deg) {
        e_reg = ceid[o0 + ln];
        s_reg = emask[e_reg] ? src[e_reg] : -1;
    }

    // quad online-softmax state
    float mS[4] = {-1e30f, -1e30f, -1e30f, -1e30f};
    float denS[4] = {0.f, 0.f, 0.f, 0.f};
    float zS[4] = {0.f, 0.f, 0.f, 0.f};
    float outS[4][8] = {};

    int i = 0;
    for (; i + 3 < deg; i += 4) {
        int si[4], ei[4], sa[4];
#pragma unroll
        for (int u = 0; u < 4; ++u) {
            si[u] = __shfl(s_reg, i + u);
            ei[u] = __shfl(e_reg, i + u);
            sa[u] = (si[u] < 0) ? 0 : si[u];
        }
        uint4 ku[4], vu[4];
        float eav[4];
#pragma unroll
        for (int u = 0; u < 4; ++u) {
            ku[u] = *(const uint4*)(kmat + (size_t)sa[u] * HDIM + d0i);
            vu[u] = *(const uint4*)(vmat + (size_t)sa[u] * HDIM + d0i);
            eav[u] = eattr[(size_t)ei[u] * EDIMC + j];
        }
        float pp[4];
#pragma unroll
        for (int u = 0; u < 4; ++u) {
            float2 k0 = b2f2(ku[u].x), k1 = b2f2(ku[u].y);
            float2 k2 = b2f2(ku[u].z), k3 = b2f2(ku[u].w);
            float p = qf[0] * k0.x + qf[1] * k0.y + qf[2] * k1.x + qf[3] * k1.y +
                      qf[4] * k2.x + qf[5] * k2.y + qf[6] * k3.x + qf[7] * k3.y;
            pp[u] = fmaf(qWl, eav[u], p);
        }
#pragma unroll
        for (int off = 8; off > 0; off >>= 1)
#pragma unroll
            for (int u = 0; u < 4; ++u) pp[u] += __shfl_xor(pp[u], off);
#pragma unroll
        for (int u = 0; u < 4; ++u) {
            float s = (si[u] < 0) ? -1e30f : pp[u] * SCALE;
            float m_new = fmaxf(mS[u], s);
            float c = __expf(mS[u] - m_new);
            float al = (si[u] < 0) ? 0.f : __expf(s - m_new);
            denS[u] = denS[u] * c + al;
            zS[u] = zS[u] * c + al * eav[u];
            float2 v0 = b2f2(vu[u].x), v1 = b2f2(vu[u].y);
            float2 v2 = b2f2(vu[u].z), v3 = b2f2(vu[u].w);
            outS[u][0] = outS[u][0] * c + al * v0.x;
            outS[u][1] = outS[u][1] * c + al * v0.y;
            outS[u][2] = outS[u][2] * c + al * v1.x;
            outS[u][3] = outS[u][3] * c + al * v1.y;
            outS[u][4] = outS[u][4] * c + al * v2.x;
            outS[u][5] = outS[u][5] * c + al * v2.y;
            outS[u][6] = outS[u][6] * c + al * v3.x;
            outS[u][7] = outS[u][7] * c + al * v3.y;
            mS[u] = m_new;
        }
    }
    for (; i < deg; ++i) {  // tail edges -> state 0
        int siA = __shfl(s_reg, i);
        int eiA = __shfl(e_reg, i);
        int sa = (siA < 0) ? 0 : siA;
        uint4 kuA = *(const uint4*)(kmat + (size_t)sa * HDIM + d0i);
        uint4 vuA = *(const uint4*)(vmat + (size_t)sa * HDIM + d0i);
        float eavA = eattr[(size_t)eiA * EDIMC + j];
        float2 ka0 = b2f2(kuA.x), ka1 = b2f2(kuA.y), ka2 = b2f2(kuA.z), ka3 = b2f2(kuA.w);
        float pA = qf[0] * ka0.x + qf[1] * ka0.y + qf[2] * ka1.x + qf[3] * ka1.y +
                   qf[4] * ka2.x + qf[5] * ka2.y + qf[6] * ka3.x + qf[7] * ka3.y;
        pA = fmaf(qWl, eavA, pA);
        pA += __shfl_xor(pA, 8);
        pA += __shfl_xor(pA, 4);
        pA += __shfl_xor(pA, 2);
        pA += __shfl_xor(pA, 1);
        float sA = (siA < 0) ? -1e30f : pA * SCALE;
        float m_new = fmaxf(mS[0], sA);
        float c = __expf(mS[0] - m_new);
        float al = (siA < 0) ? 0.f : __expf(sA - m_new);
        denS[0] = denS[0] * c + al;
        zS[0] = zS[0] * c + al * eavA;
        float2 v0 = b2f2(vuA.x), v1 = b2f2(vuA.y), v2 = b2f2(vuA.z), v3 = b2f2(vuA.w);
        outS[0][0] = outS[0][0] * c + al * v0.x;
        outS[0][1] = outS[0][1] * c + al * v0.y;
        outS[0][2] = outS[0][2] * c + al * v1.x;
        outS[0][3] = outS[0][3] * c + al * v1.y;
        outS[0][4] = outS[0][4] * c + al * v2.x;
        outS[0][5] = outS[0][5] * c + al * v2.y;
        outS[0][6] = outS[0][6] * c + al * v3.x;
        outS[0][7] = outS[0][7] * c + al * v3.y;
        mS[0] = m_new;
    }
    // exact merge of the four states
    float mT = fmaxf(fmaxf(mS[0], mS[1]), fmaxf(mS[2], mS[3]));
    float cS[4];
#pragma unroll
    for (int u = 0; u < 4; ++u) cS[u] = __expf(mS[u] - mT);
    float den = 0.f, z = 0.f;
    float out[8] = {0.f, 0.f, 0.f, 0.f, 0.f, 0.f, 0.f, 0.f};
#pragma unroll
    for (int u = 0; u < 4; ++u) {
        den += denS[u] * cS[u];
        z += zS[u] * cS[u];
#pragma unroll
        for (int d = 0; d < 8; ++d) out[d] += outS[u][d] * cS[u];
    }

    float inv = 1.f / fmaxf(den, 1e-16f);
    z *= inv;
#pragma unroll
    for (int d = 0; d < 8; ++d) out[d] *= inv;

    // eproj
#pragma unroll
    for (int jj = 0; jj < EDIMC; ++jj) {
        float zjj = __shfl(z, h * 16 + jj);
        const float4* wp = (const float4*)(We + (size_t)jj * HDIM + d0i);
        float4 wa = wp[0], wb4 = wp[1];
        out[0] = fmaf(zjj, wa.x, out[0]);
        out[1] = fmaf(zjj, wa.y, out[1]);
        out[2] = fmaf(zjj, wa.z, out[2]);
        out[3] = fmaf(zjj, wa.w, out[3]);
        out[4] = fmaf(zjj, wb4.x, out[4]);
        out[5] = fmaf(zjj, wb4.y, out[5]);
        out[6] = fmaf(zjj, wb4.z, out[6]);
        out[7] = fmaf(zjj, wb4.w, out[7]);
    }

    // beta gate + gated combine
    uint4 xu = *(const uint4*)(xr + (size_t)n * HDIM + d0i);
    float2 x0 = b2f2(xu.x), x1 = b2f2(xu.y), x2 = b2f2(xu.z), x3 = b2f2(xu.w);
    float xf[8] = {x0.x, x0.y, x1.x, x1.y, x2.x, x2.y, x3.x, x3.y};
    const float4* w0p = (const float4*)(Wb + d0i);
    const float4* w1p = (const float4*)(Wb + HDIM + d0i);
    const float4* w2p = (const float4*)(Wb + 2 * HDIM + d0i);
    float4 wa0 = w0p[0], wa1 = w0p[1];
    float4 wb0 = w1p[0], wb1 = w1p[1];
    float4 wc0 = w2p[0], wc1 = w2p[1];
    float w0f[8] = {wa0.x, wa0.y, wa0.z, wa0.w, wa1.x, wa1.y, wa1.z, wa1.w};
    float w1f[8] = {wb0.x, wb0.y, wb0.z, wb0.w, wb1.x, wb1.y, wb1.z, wb1.w};
    float w2f[8] = {wc0.x, wc0.y, wc0.z, wc0.w, wc1.x, wc1.y, wc1.z, wc1.w};
    float part = 0.f;
#pragma unroll
    for (int d = 0; d < 8; ++d)
        part += out[d] * w0f[d] + xf[d] * w1f[d] + (out[d] - xf[d]) * w2f[d];
#pragma unroll
    for (int o = 32; o > 0; o >>= 1) part += __shfl_xor(part, o);
    float bg = 1.f / (1.f + __expf(-part));
    uint4 res;
    res.x = pack2(bg * xf[0] + (1.f - bg) * out[0], bg * xf[1] + (1.f - bg) * out[1]);
    res.y = pack2(bg * xf[2] + (1.f - bg) * out[2], bg * xf[3] + (1.f - bg) * out[3]);
    res.z = pack2(bg * xf[4] + (1.f - bg) * out[4], bg * xf[5] + (1.f - bg) * out[5]);
    res.w = pack2(bg * xf[6] + (1.f - bg) * out[6], bg * xf[7] + (1.f - bg) * out[7]);
    *(uint4*)(h2 + (size_t)n * HDIM + d0i) = res;
}

// ---------------- TopK pool, split for parallelism ----------------------------------
__global__ __launch_bounds__(256) void k_pool_rank(const float* __restrict__ pwv,
                                                   const float* __restrict__ h,
                                                   int* __restrict__ nmask,
                                                   int* __restrict__ emask,  // null => skip
                                                   const int* __restrict__ src,
                                                   const int* __restrict__ dst,
                                                   float* __restrict__ fbuf, int kc) {
    __shared__ float smS[NPGC];
    __shared__ int keepS[NPGC];
    int g = blockIdx.x, t = threadIdx.x;
    int n = g * NPGC + t;
    const float* hr = h + (size_t)n * FF;
    float nw2 = 0.f, dv = 0.f;
#pragma unroll
    for (int i = 0; i < FF; i += 4) {
        float4 wv = *(const float4*)(pwv + i);
        float4 hv = *(const float4*)(hr + i);
        nw2 += wv.x * wv.x + wv.y * wv.y + wv.z * wv.z + wv.w * wv.w;
        dv += hv.x * wv.x + hv.y * wv.y + hv.z * wv.z + hv.w * wv.w;
    }
    float s = tanhf(dv / sqrtf(nw2));
    int old = nmask[n];
    smS[t] = old ? s : -INFINITY;
    __syncthreads();
    float mys = smS[t];
    int rank = 0;
    for (int j = 0; j < NPGC; ++j) {
        float o = smS[j];
        rank += (o > mys) || (o == mys && j < t);  // stable argsort tie-break
    }
    int kp = (rank < kc) && old;  // ranks unique -> exactly kc kept per graph
    keepS[t] = kp;
    nmask[n] = kp;
    fbuf[n] = s * (float)kp;
    __syncthreads();
    if (emask) {
        int base = g * EGC;
        for (int ee = t; ee < EGC; ee += 256) {
            int e = base + ee;
            emask[e] = emask[e] && keepS[src[e] - g * NPGC] && keepS[dst[e] - g * NPGC];
        }
    }
}

// apply: grid (BB,4): scale, optional bf16 emit, per-dim max/sum partials (64 nodes).
__global__ __launch_bounds__(256) void k_pool_apply(const float* __restrict__ h,
                                                    unsigned short* __restrict__ hbf,
                                                    const float* __restrict__ fbuf,
                                                    const int* __restrict__ nmask,
                                                    float* __restrict__ pmax,
                                                    float* __restrict__ psum, int emit) {
    __shared__ float mS[4][128];
    __shared__ float sS[4][128];
    int g = blockIdx.x, seg = blockIdx.y, t = threadIdx.x;
    int l = t & 63, quar = t >> 6;
    int d2 = l * 2;
    int nbase = g * NPGC + seg * 64 + quar * 16;
    float mx0 = -1e30f, mx1 = -1e30f, sm0 = 0.f, sm1 = 0.f;
#pragma unroll 4
    for (int i = 0; i < 16; ++i) {
        int n = nbase + i;
        float f = fbuf[n];
        int kp = nmask[n];
        float2 hv = *(const float2*)(h + (size_t)n * FF + d2);
        float v0 = hv.x * f, v1 = hv.y * f;
        if (emit) *(unsigned*)(hbf + (size_t)n * FF + d2) = pack2(v0, v1);
        if (kp) {
            mx0 = fmaxf(mx0, v0);
            mx1 = fmaxf(mx1, v1);
            sm0 += v0;
            sm1 += v1;
        }
    }
    mS[quar][d2] = mx0;
    mS[quar][d2 + 1] = mx1;
    sS[quar][d2] = sm0;
    sS[quar][d2 + 1] = sm1;
    __syncthreads();
    if (t < 128) {
        float m = fmaxf(fmaxf(mS[0][t], mS[1][t]), fmaxf(mS[2][t], mS[3][t]));
        float s = sS[0][t] + sS[1][t] + sS[2][t] + sS[3][t];
        pmax[((size_t)g * 4 + seg) * 128 + t] = m;
        psum[((size_t)g * 4 + seg) * 128 + t] = s;
    }
}

// final 32x10 layer (fp32, tiny)
__global__ __launch_bounds__(256) void k_mlp_wave(const float* __restrict__ A,
                                                  const float* __restrict__ W,
                                                  const float* __restrict__ b,
                                                  float* __restrict__ C,
                                                  int M, int N, int K, int relu) {
    int wid = (blockIdx.x * 256 + threadIdx.x) >> 6;
    int lane = threadIdx.x & 63;
    if (wid >= M * N) return;
    int r = wid / N, c = wid % N;
    const float* Arow = A + (size_t)r * K;
    float acc = 0.f;
    for (int kk = lane; kk < K; kk += 64)
        acc = fmaf(Arow[kk], W[(size_t)kk * N + c], acc);
    acc = waveReduceSum(acc);
    if (lane == 0) {
        acc += b[c];
        C[wid] = relu ? fmaxf(acc, 0.f) : acc;
    }
}

// ---------------- host launch ----------------
extern "C" void kernel_launch(void* const* d_in, const int* in_sizes, int n_in,
                              void* d_out, int out_size, void* d_ws, size_t ws_size,
                              hipStream_t stream) {
    const float* x = (const float*)d_in[0];
    const float* eattr = (const float*)d_in[1];
    const int* eidx = (const int*)d_in[2];
    const float* esm = (const float*)d_in[4];
    const float* Wq = (const float*)d_in[5];
    const float* bq = (const float*)d_in[6];
    const float* Wk = (const float*)d_in[7];
    const float* bk = (const float*)d_in[8];
    const float* Wv = (const float*)d_in[9];
    const float* bv = (const float*)d_in[10];
    const float* We = (const float*)d_in[11];
    const float* Wsk = (const float*)d_in[12];
    const float* bsk = (const float*)d_in[13];
    const float* Wbe = (const float*)d_in[14];
    const float* Wt = (const float*)d_in[15];
    const float* bt = (const float*)d_in[16];
    const float* gam = (const float*)d_in[17];
    const float* bet = (const float*)d_in[18];
    const float* rme = (const float*)d_in[19];
    const float* rva = (const float*)d_in[20];
    const float* pw = (const float*)d_in[21];
    const float* W1 = (const float*)d_in[22];
    const float* b1 = (const float*)d_in[23];
    const float* W2 = (const float*)d_in[24];
    const float* b2 = (const float*)d_in[25];
    const float* W3 = (const float*)d_in[26];
    const float* b3 = (const float*)d_in[27];
    const int* srcp = eidx;
    const int* dstp = eidx + NEDGE;

    char* p = (char*)d_ws;
    auto alloc = [&](size_t bytes) -> void* {
        void* r = (void*)p;
        p += (bytes + 255) & ~(size_t)255;
        return r;
    };
    float* hA = (float*)alloc((size_t)NNODE * FF * 4);
    float* hB = (float*)alloc((size_t)NNODE * FF * 4);
    float* fbuf = (float*)alloc((size_t)NNODE * 4);
    float* pmax0 = (float*)alloc((size_t)BB * 4 * 128 * 4);
    float* psum0 = (float*)alloc((size_t)BB * 4 * 128 * 4);
    float* pmax1 = (float*)alloc((size_t)BB * 4 * 128 * 4);
    float* psum1 = (float*)alloc((size_t)BB * 4 * 128 * 4);
    float* g2 = (float*)alloc((size_t)BB * 512 * 4);
    float* g3 = (float*)alloc((size_t)BB * 256 * 4);
    float* cp = (float*)alloc((size_t)8 * 32 * 512 * 4);
    int* nmask = (int*)alloc((size_t)NNODE * 4);
    int* emask = (int*)alloc((size_t)NEDGE * 4);
    int* coff = (int*)alloc((size_t)(NNODE + 1) * 4);
    int* ceid = (int*)alloc((size_t)NEDGE * 4);
    // bf16 buffers
    unsigned short* xb = (unsigned short*)alloc((size_t)NNODE * FF * 2);
    unsigned short* hbf = (unsigned short*)alloc((size_t)NNODE * FF * 2);
    unsigned short* qb16 = (unsigned short*)alloc((size_t)NNODE * HDIM * 2);
    unsigned short* kb16 = (unsigned short*)alloc((size_t)NNODE * HDIM * 2);
    unsigned short* vb16 = (unsigned short*)alloc((size_t)NNODE * HDIM * 2);
    unsigned short* xrb16 = (unsigned short*)alloc((size_t)NNODE * HDIM * 2);
    unsigned short* h2b16 = (unsigned short*)alloc((size_t)NNODE * HDIM * 2);
    unsigned short* wqb = (unsigned short*)alloc((size_t)4 * 65536 * 2);
    unsigned short* wkb = (unsigned short*)alloc((size_t)4 * 65536 * 2);
    unsigned short* wvb = (unsigned short*)alloc((size_t)4 * 65536 * 2);
    unsigned short* wskb = (unsigned short*)alloc((size_t)4 * 65536 * 2);
    unsigned short* wtb = (unsigned short*)alloc((size_t)4 * 65536 * 2);
    unsigned short* w1b = (unsigned short*)alloc((size_t)786432 * 2);
    unsigned short* w2b = (unsigned short*)alloc((size_t)131072 * 2);
    unsigned short* g1b = (unsigned short*)alloc((size_t)BB * 1536 * 2);
    unsigned short* g2b = (unsigned short*)alloc((size_t)BB * 512 * 2);

    k_convert_setup<<<12832, 256, 0, stream>>>(x, Wq, Wk, Wv, Wsk, Wt, W1, W2,
                                               xb, wqb, wkb, wvb, wskb, wtb, w1b, w2b,
                                               dstp, emask, nmask, coff, ceid);

    auto conv = [&](int li, const unsigned short* hin_b, float* hout) {
        dim3 gq(64, 4, 4);
        k_qkvs_mfma<<<gq, 256, 0, stream>>>(
            hin_b, wqb + (size_t)li * 65536, wkb + (size_t)li * 65536,
            wvb + (size_t)li * 65536, wskb + (size_t)li * 65536,
            bq + li * HDIM, bk + li * HDIM, bv + li * HDIM, bsk + li * HDIM,
            qb16, kb16, vb16, xrb16);
        const float* WeL = We + (size_t)li * EDIMC * HDIM;
        k_attn_wave<<<NNODE / 4, 256, 0, stream>>>(qb16, kb16, vb16, xrb16, eattr, WeL,
                                                   Wbe + (size_t)li * 3 * HDIM,
                                                   srcp, coff, ceid, emask, h2b16);
        k_out_mfma<<<NNODE / 32, 128, 0, stream>>>(
            h2b16, wtb + (size_t)li * 65536, bt + li * FF, gam + li * FF,
            bet + li * FF, rme + li * FF, rva + li * FF, hout, hbf);
    };

    auto pool = [&](int pi, const float* h, float* pmax, float* psum, int kc, bool updE,
                    int emit) {
        k_pool_rank<<<BB, 256, 0, stream>>>(pw + pi * FF, h, nmask,
                                            updE ? emask : nullptr, srcp, dstp, fbuf, kc);
        k_pool_apply<<<dim3(BB, 4), 256, 0, stream>>>(h, hbf, fbuf, nmask, pmax, psum, emit);
    };

    // layer 4 of the reference is dead code (output feeds nothing) — skipped.
    conv(0, xb, hA);
    conv(1, hbf, hB);
    pool(0, hB, pmax0, psum0, NPGC / 2, true, 1);   // emits bf16 h for conv2
    conv(2, hbf, hA);
    conv(3, hbf, hB);
    pool(1, hB, pmax1, psum1, NPGC / 4, false, 0);  // nothing downstream reads h

    k_g1<<<BB * 1536 / 256, 256, 0, stream>>>(pmax0, psum0, pmax1, psum1, esm, g1b);
    k_mlp_mfma<<<dim3(2, 8), 256, 0, stream>>>(g1b, w1b, cp, 512, 1536, 8);
    k_mlp_fix<<<BB * 512 / 256, 256, 0, stream>>>(cp, b1, g2, g2b, BB * 512, 512, 8, 1);
    k_mlp_mfma<<<dim3(1, 8), 256, 0, stream>>>(g2b, w2b, cp, 256, 512, 8);
    k_mlp_fix<<<BB * 256 / 256, 256, 0, stream>>>(cp, b2, g3, nullptr, BB * 256, 256, 8, 1);
    k_mlp_wave<<<(BB * 10 * 64 + 255) / 256, 256, 0, stream>>>(g3, W3, b3, (float*)d_out,
                                                               BB, 10, 256, 0);
}

// Round 16
// 458.185 us; speedup vs baseline: 1.1067x; 1.0719x over previous
//
#include <hip/hip_runtime.h>
#include <math.h>

#define BB 32
#define NPGC 256
#define FF 128
#define EDIMC 16
#define ESMC 1280
#define NNODE 8192
#define NEDGE 65536
#define EGC 2048
#define NH 4
#define DH 128
#define HDIM 512
#define SCALE 0.088388347648318447f  // 1/sqrt(128)

typedef __attribute__((ext_vector_type(8))) short bf16x8;
typedef __attribute__((ext_vector_type(4))) float f32x4;

__device__ __forceinline__ float waveReduceSum(float v) {
#pragma unroll
    for (int o = 32; o > 0; o >>= 1) v += __shfl_down(v, o);
    return v;
}

// fp32 -> bf16 (RNE), raw ushort
__device__ __forceinline__ unsigned short f2b(float f) {
    unsigned u = __builtin_bit_cast(unsigned, f);
    return (unsigned short)((u + 0x7fffu + ((u >> 16) & 1u)) >> 16);
}
__device__ __forceinline__ unsigned pack2(float lo, float hi) {
    return (unsigned)f2b(lo) | ((unsigned)f2b(hi) << 16);
}
// packed pair of bf16 (as uint) -> two floats
__device__ __forceinline__ float2 b2f2(unsigned u) {
    float lo = __builtin_bit_cast(float, u << 16);
    float hi = __builtin_bit_cast(float, u & 0xffff0000u);
    return make_float2(lo, hi);
}

// ---------------- FUSED convert + setup -------------------------------------------
__global__ __launch_bounds__(256) void k_convert_setup(
    const float* __restrict__ x, const float* __restrict__ Wq,
    const float* __restrict__ Wk, const float* __restrict__ Wv,
    const float* __restrict__ Wsk, const float* __restrict__ Wt,
    const float* __restrict__ W1, const float* __restrict__ W2,
    unsigned short* __restrict__ xb, unsigned short* __restrict__ wqb,
    unsigned short* __restrict__ wkb, unsigned short* __restrict__ wvb,
    unsigned short* __restrict__ wskb, unsigned short* __restrict__ wtb,
    unsigned short* __restrict__ w1b, unsigned short* __restrict__ w2b,
    const int* __restrict__ dst, int* __restrict__ emask, int* __restrict__ nmask,
    int* __restrict__ coff, int* __restrict__ ceid) {
    __shared__ int cntS[NPGC];
    __shared__ int scanS[NPGC];
    __shared__ int offS[NPGC];
    if (blockIdx.x >= 12800) {
        int g = blockIdx.x - 12800, t = threadIdx.x;
        cntS[t] = 0;
        nmask[g * NPGC + t] = 1;
        __syncthreads();
        int base = g * EGC;
#pragma unroll
        for (int i = 0; i < EGC / 256; ++i) {
            int e = base + i * 256 + t;
            emask[e] = 1;
            atomicAdd(&cntS[dst[e] - g * NPGC], 1);
        }
        __syncthreads();
        scanS[t] = cntS[t];
        __syncthreads();
        for (int off = 1; off < NPGC; off <<= 1) {
            int v = scanS[t];
            if (t >= off) v += scanS[t - off];
            __syncthreads();
            scanS[t] = v;
            __syncthreads();
        }
        int excl = scanS[t] - cntS[t];
        offS[t] = excl;
        coff[g * NPGC + t] = base + excl;
        if (g == 0 && t == 0) coff[NNODE] = NEDGE;
        cntS[t] = 0;
        __syncthreads();
#pragma unroll
        for (int i = 0; i < EGC / 256; ++i) {
            int e = base + i * 256 + t;
            int d = dst[e] - g * NPGC;
            int pos = atomicAdd(&cntS[d], 1);
            ceid[base + offS[d] + pos] = e;
        }
        return;
    }
    int idx = blockIdx.x * 256 + threadIdx.x;
    if (idx < 1048576) { xb[idx] = f2b(x[idx]); return; }
    idx -= 1048576;
    if (idx < 1048576) {  // Wq/Wk/Wv/Wskip: [li][128][512] -> [li][512][128]
        int fam = idx >> 18, local = idx & 262143;
        int li = local >> 16, rem = local & 65535;
        int n = rem >> 7, k = rem & 127;
        const float* S = (fam == 0) ? Wq : (fam == 1) ? Wk : (fam == 2) ? Wv : Wsk;
        unsigned short* D = (fam == 0) ? wqb : (fam == 1) ? wkb : (fam == 2) ? wvb : wskb;
        D[local] = f2b(S[(size_t)li * 65536 + (size_t)k * 512 + n]);
        return;
    }
    idx -= 1048576;
    if (idx < 262144) {  // Wt: [li][512][128] -> [li][128][512]
        int li = idx >> 16, rem = idx & 65535;
        int n = rem >> 9, k = rem & 511;
        wtb[idx] = f2b(Wt[(size_t)li * 65536 + (size_t)k * 128 + n]);
        return;
    }
    idx -= 262144;
    if (idx < 786432) {  // W1: [1536][512] -> [512][1536]
        int n = idx / 1536, k = idx % 1536;
        w1b[idx] = f2b(W1[(size_t)k * 512 + n]);
        return;
    }
    idx -= 786432;
    {  // W2: [512][256] -> [256][512]
        int n = idx >> 9, k = idx & 511;
        w2b[idx] = f2b(W2[(size_t)k * 256 + n]);
    }
}

// ---------------- fused q/k/v/skip GEMM via MFMA bf16 -> bf16 outputs ----------------
__global__ __launch_bounds__(256) void k_qkvs_mfma(
    const unsigned short* __restrict__ hb,
    const unsigned short* __restrict__ wq, const unsigned short* __restrict__ wk,
    const unsigned short* __restrict__ wv, const unsigned short* __restrict__ wsk,
    const float* __restrict__ bq, const float* __restrict__ bk,
    const float* __restrict__ bv, const float* __restrict__ bsk,
    unsigned short* __restrict__ oq, unsigned short* __restrict__ ok,
    unsigned short* __restrict__ ov, unsigned short* __restrict__ osk) {
    const unsigned short* W;
    const float* bias;
    unsigned short* out;
    if (blockIdx.z == 0) { W = wq; bias = bq; out = oq; }
    else if (blockIdx.z == 1) { W = wk; bias = bk; out = ok; }
    else if (blockIdx.z == 2) { W = wv; bias = bv; out = ov; }
    else { W = wsk; bias = bsk; out = osk; }
    int lane = threadIdx.x & 63, wave = threadIdx.x >> 6;
    int quad = lane >> 4, m = lane & 15;
    int xcdx = blockIdx.x;  // [0,64): graph g = (bi&7)+8*((bi>>3)&3), half = bi>>5
    int g = (xcdx & 7) + 8 * ((xcdx >> 3) & 3);
    int half = xcdx >> 5;
    int rowbase = g * NPGC + half * 128 + (wave >> 1) * 64;
    int colbase = blockIdx.y * 128 + (wave & 1) * 64;
    f32x4 zero = {0.f, 0.f, 0.f, 0.f};
    f32x4 acc[4][4];
#pragma unroll
    for (int i = 0; i < 4; ++i)
#pragma unroll
        for (int j = 0; j < 4; ++j) acc[i][j] = zero;
#pragma unroll
    for (int ks = 0; ks < 4; ++ks) {
        int k0 = ks * 32 + quad * 8;
        bf16x8 af[4], bfr[4];
#pragma unroll
        for (int tm = 0; tm < 4; ++tm)
            af[tm] = *(const bf16x8*)(hb + (size_t)(rowbase + tm * 16 + m) * FF + k0);
#pragma unroll
        for (int tn = 0; tn < 4; ++tn)
            bfr[tn] = *(const bf16x8*)(W + (size_t)(colbase + tn * 16 + m) * FF + k0);
#pragma unroll
        for (int tm = 0; tm < 4; ++tm)
#pragma unroll
            for (int tn = 0; tn < 4; ++tn)
                acc[tm][tn] = __builtin_amdgcn_mfma_f32_16x16x32_bf16(af[tm], bfr[tn],
                                                                      acc[tm][tn], 0, 0, 0);
    }
#pragma unroll
    for (int tn = 0; tn < 4; ++tn) {
        int col = colbase + tn * 16 + m;
        float bc = bias[col];
#pragma unroll
        for (int tm = 0; tm < 4; ++tm)
#pragma unroll
            for (int r = 0; r < 4; ++r)
                out[(size_t)(rowbase + tm * 16 + quad * 4 + r) * HDIM + col] =
                    f2b(acc[tm][tn][r] + bc);
    }
}

// ---------------- output GEMM (h2@Wt) via MFMA + relu + BN epilogue ------------------
// hout may be null (layers whose fp32 h is never read) — skips the dead store.
__global__ __launch_bounds__(128) void k_out_mfma(
    const unsigned short* __restrict__ h2b, const unsigned short* __restrict__ wt,
    const float* __restrict__ bt_, const float* __restrict__ gam_,
    const float* __restrict__ bet_, const float* __restrict__ rme_,
    const float* __restrict__ rva_, float* __restrict__ hout,
    unsigned short* __restrict__ hbf) {
    int lane = threadIdx.x & 63, wave = threadIdx.x >> 6;
    int quad = lane >> 4, m = lane & 15;
    int bi = blockIdx.x;  // [0,256)
    int g = (bi & 7) + 8 * ((bi >> 3) & 3);
    int sub = bi >> 5;    // [0,8)
    int rowbase = g * NPGC + sub * 32;
    int colbase = wave * 64;
    f32x4 zero = {0.f, 0.f, 0.f, 0.f};
    f32x4 acc[2][4];
#pragma unroll
    for (int i = 0; i < 2; ++i)
#pragma unroll
        for (int j = 0; j < 4; ++j) acc[i][j] = zero;
    for (int ks = 0; ks < 16; ++ks) {
        int k0 = ks * 32 + quad * 8;
        bf16x8 af[2], bfr[4];
#pragma unroll
        for (int tm = 0; tm < 2; ++tm)
            af[tm] = *(const bf16x8*)(h2b + (size_t)(rowbase + tm * 16 + m) * HDIM + k0);
#pragma unroll
        for (int tn = 0; tn < 4; ++tn)
            bfr[tn] = *(const bf16x8*)(wt + (size_t)(colbase + tn * 16 + m) * HDIM + k0);
#pragma unroll
        for (int tm = 0; tm < 2; ++tm)
#pragma unroll
            for (int tn = 0; tn < 4; ++tn)
                acc[tm][tn] = __builtin_amdgcn_mfma_f32_16x16x32_bf16(af[tm], bfr[tn],
                                                                      acc[tm][tn], 0, 0, 0);
    }
#pragma unroll
    for (int tn = 0; tn < 4; ++tn) {
        int col = colbase + tn * 16 + m;
        float bc = bt_[col];
        float sc = gam_[col] * rsqrtf(rva_[col] + 1e-5f);
        float sh = bet_[col] - rme_[col] * sc;
#pragma unroll
        for (int tm = 0; tm < 2; ++tm)
#pragma unroll
            for (int r = 0; r < 4; ++r) {
                size_t o = (size_t)(rowbase + tm * 16 + quad * 4 + r) * FF + col;
                float v = fmaxf(acc[tm][tn][r] + bc, 0.f) * sc + sh;
                if (hout) hout[o] = v;
                hbf[o] = f2b(v);
            }
    }
}

// ---------------- MLP via MFMA: A[32][K] @ W^T[N][K], split-K partials ---------------
__global__ __launch_bounds__(256) void k_mlp_mfma(const unsigned short* __restrict__ A,
                                                  const unsigned short* __restrict__ Wt,
                                                  float* __restrict__ cp,
                                                  int N, int K, int KS) {
    int lane = threadIdx.x & 63, wave = threadIdx.x >> 6;
    int quad = lane >> 4, m = lane & 15;
    int colbase = blockIdx.x * 256 + wave * 64;
    int kc = K / KS;
    int k0b = blockIdx.y * kc;
    f32x4 zero = {0.f, 0.f, 0.f, 0.f};
    f32x4 acc[2][4];
#pragma unroll
    for (int i = 0; i < 2; ++i)
#pragma unroll
        for (int j = 0; j < 4; ++j) acc[i][j] = zero;
    for (int ks = 0; ks < kc / 32; ++ks) {
        int k0 = k0b + ks * 32 + quad * 8;
        bf16x8 a0 = *(const bf16x8*)(A + (size_t)m * K + k0);
        bf16x8 a1 = *(const bf16x8*)(A + (size_t)(16 + m) * K + k0);
        bf16x8 bfr[4];
#pragma unroll
        for (int tn = 0; tn < 4; ++tn)
            bfr[tn] = *(const bf16x8*)(Wt + (size_t)(colbase + tn * 16 + m) * K + k0);
#pragma unroll
        for (int tn = 0; tn < 4; ++tn) {
            acc[0][tn] = __builtin_amdgcn_mfma_f32_16x16x32_bf16(a0, bfr[tn], acc[0][tn], 0, 0, 0);
            acc[1][tn] = __builtin_amdgcn_mfma_f32_16x16x32_bf16(a1, bfr[tn], acc[1][tn], 0, 0, 0);
        }
    }
#pragma unroll
    for (int tm = 0; tm < 2; ++tm)
#pragma unroll
        for (int tn = 0; tn < 4; ++tn)
#pragma unroll
            for (int r = 0; r < 4; ++r)
                cp[((size_t)blockIdx.y * 32 + tm * 16 + quad * 4 + r) * N +
                   colbase + tn * 16 + m] = acc[tm][tn][r];
}

__global__ void k_mlp_fix(const float* __restrict__ cp, const float* __restrict__ b,
                          float* __restrict__ C, unsigned short* __restrict__ Cb,
                          int MN, int N, int KS, int relu) {
    int i = blockIdx.x * 256 + threadIdx.x;
    if (i >= MN) return;
    float acc = b[i % N];
    for (int s = 0; s < KS; ++s) acc += cp[(size_t)s * MN + i];
    if (relu) acc = fmaxf(acc, 0.f);
    C[i] = acc;
    if (Cb) Cb[i] = f2b(acc);
}

// build g1 = [gmax0+gmax1 | gmean0+gmean1 | esm] in bf16 [32][1536]
__global__ void k_g1(const float* __restrict__ pmax0, const float* __restrict__ psum0,
                     const float* __restrict__ pmax1, const float* __restrict__ psum1,
                     const float* __restrict__ esm, unsigned short* __restrict__ g1b) {
    int i = blockIdx.x * 256 + threadIdx.x;  // 32*1536
    int r = i / 1536, c = i % 1536;
    float v;
    if (c < 128) {
        float m0 = -1e30f, m1 = -1e30f;
#pragma unroll
        for (int q = 0; q < 4; ++q) {
            m0 = fmaxf(m0, pmax0[((size_t)r * 4 + q) * 128 + c]);
            m1 = fmaxf(m1, pmax1[((size_t)r * 4 + q) * 128 + c]);
        }
        v = m0 + m1;
    } else if (c < 256) {
        int d = c - 128;
        float s0 = 0.f, s1 = 0.f;
#pragma unroll
        for (int q = 0; q < 4; ++q) {
            s0 += psum0[((size_t)r * 4 + q) * 128 + d];
            s1 += psum1[((size_t)r * 4 + q) * 128 + d];
        }
        v = s0 * (1.f / 128.f) + s1 * (1.f / 64.f);  // count==kc (unique ranks)
    } else {
        v = esm[(size_t)r * ESMC + c - 256];
    }
    g1b[i] = f2b(v);
}

// ---------------- WAVE-PER-NODE attention: online softmax, 2-way ILP (round-13 best) -
__global__ __launch_bounds__(256) void k_attn_wave(
    const unsigned short* __restrict__ q, const unsigned short* __restrict__ kmat,
    const unsigned short* __restrict__ vmat, const unsigned short* __restrict__ xr,
    const float* __restrict__ eattr, const float* __restrict__ We,
    const float* __restrict__ Wb,
    const int* __restrict__ src, const int* __restrict__ coff,
    const int* __restrict__ ceid, const int* __restrict__ emask,
    unsigned short* __restrict__ h2) {
    int wv = threadIdx.x >> 6, ln = threadIdx.x & 63;
    int bi = blockIdx.x;  // [0,2048)
    int g = (bi & 7) + 8 * ((bi >> 3) & 3);
    int sub = bi >> 5;    // [0,64)
    int n = g * NPGC + sub * 4 + wv;
    int h = ln >> 4, j = ln & 15;
    int d0i = ln * 8;
    int o0 = coff[n];
    int deg = coff[n + 1] - o0;
    if (deg > 64) deg = 64;

    uint4 qu = *(const uint4*)(q + (size_t)n * HDIM + d0i);
    float2 q0 = b2f2(qu.x), q1 = b2f2(qu.y), q2 = b2f2(qu.z), q3 = b2f2(qu.w);
    float qf[8] = {q0.x, q0.y, q1.x, q1.y, q2.x, q2.y, q3.x, q3.y};

    // qW in-register (butterfly within 16-lane head groups)
    float qp[16];
#pragma unroll
    for (int jj = 0; jj < EDIMC; ++jj) {
        const float4* wp = (const float4*)(We + (size_t)jj * HDIM + d0i);
        float4 wa = wp[0], wb4 = wp[1];
        qp[jj] = qf[0] * wa.x + qf[1] * wa.y + qf[2] * wa.z + qf[3] * wa.w +
                 qf[4] * wb4.x + qf[5] * wb4.y + qf[6] * wb4.z + qf[7] * wb4.w;
    }
#pragma unroll
    for (int off = 1; off < 16; off <<= 1)
#pragma unroll
        for (int jj = 0; jj < EDIMC; ++jj) qp[jj] += __shfl_xor(qp[jj], off);
    float qWl = qp[j];

    // lane-owned edge (clamped-safe defaults for absent lanes)
    int e_reg = 0, s_reg = -1;
    if (ln < deg) {
        e_reg = ceid[o0 + ln];
        s_reg = emask[e_reg] ? src[e_reg] : -1;
    }

    // dual online-softmax state
    float mA = -1e30f, denA = 0.f, zA = 0.f;
    float mB = -1e30f, denB = 0.f, zB = 0.f;
    float outA[8] = {0.f, 0.f, 0.f, 0.f, 0.f, 0.f, 0.f, 0.f};
    float outB[8] = {0.f, 0.f, 0.f, 0.f, 0.f, 0.f, 0.f, 0.f};

    int i = 0;
    for (; i + 1 < deg; i += 2) {
        int siA = __shfl(s_reg, i), siB = __shfl(s_reg, i + 1);
        int eiA = __shfl(e_reg, i), eiB = __shfl(e_reg, i + 1);
        int sa = (siA < 0) ? 0 : siA;
        int sb = (siB < 0) ? 0 : siB;
        // all six loads issued together, no branches
        uint4 kuA = *(const uint4*)(kmat + (size_t)sa * HDIM + d0i);
        uint4 vuA = *(const uint4*)(vmat + (size_t)sa * HDIM + d0i);
        uint4 kuB = *(const uint4*)(kmat + (size_t)sb * HDIM + d0i);
        uint4 vuB = *(const uint4*)(vmat + (size_t)sb * HDIM + d0i);
        float eavA = eattr[(size_t)eiA * EDIMC + j];
        float eavB = eattr[(size_t)eiB * EDIMC + j];
        // scores (independent -> interleaved shfl reductions)
        float2 ka0 = b2f2(kuA.x), ka1 = b2f2(kuA.y), ka2 = b2f2(kuA.z), ka3 = b2f2(kuA.w);
        float2 kb0 = b2f2(kuB.x), kb1 = b2f2(kuB.y), kb2 = b2f2(kuB.z), kb3 = b2f2(kuB.w);
        float pA = qf[0] * ka0.x + qf[1] * ka0.y + qf[2] * ka1.x + qf[3] * ka1.y +
                   qf[4] * ka2.x + qf[5] * ka2.y + qf[6] * ka3.x + qf[7] * ka3.y;
        float pB = qf[0] * kb0.x + qf[1] * kb0.y + qf[2] * kb1.x + qf[3] * kb1.y +
                   qf[4] * kb2.x + qf[5] * kb2.y + qf[6] * kb3.x + qf[7] * kb3.y;
        pA = fmaf(qWl, eavA, pA);
        pB = fmaf(qWl, eavB, pB);
        pA += __shfl_xor(pA, 8);  pB += __shfl_xor(pB, 8);
        pA += __shfl_xor(pA, 4);  pB += __shfl_xor(pB, 4);
        pA += __shfl_xor(pA, 2);  pB += __shfl_xor(pB, 2);
        pA += __shfl_xor(pA, 1);  pB += __shfl_xor(pB, 1);
        float sA = (siA < 0) ? -1e30f : pA * SCALE;
        float sB = (siB < 0) ? -1e30f : pB * SCALE;
        // state A update
        {
            float m_new = fmaxf(mA, sA);
            float c = __expf(mA - m_new);
            float al = (siA < 0) ? 0.f : __expf(sA - m_new);
            denA = denA * c + al;
            zA = zA * c + al * eavA;
            float2 v0 = b2f2(vuA.x), v1 = b2f2(vuA.y), v2 = b2f2(vuA.z), v3 = b2f2(vuA.w);
            outA[0] = outA[0] * c + al * v0.x;
            outA[1] = outA[1] * c + al * v0.y;
            outA[2] = outA[2] * c + al * v1.x;
            outA[3] = outA[3] * c + al * v1.y;
            outA[4] = outA[4] * c + al * v2.x;
            outA[5] = outA[5] * c + al * v2.y;
            outA[6] = outA[6] * c + al * v3.x;
            outA[7] = outA[7] * c + al * v3.y;
            mA = m_new;
        }
        // state B update (independent of A)
        {
            float m_new = fmaxf(mB, sB);
            float c = __expf(mB - m_new);
            float al = (siB < 0) ? 0.f : __expf(sB - m_new);
            denB = denB * c + al;
            zB = zB * c + al * eavB;
            float2 v0 = b2f2(vuB.x), v1 = b2f2(vuB.y), v2 = b2f2(vuB.z), v3 = b2f2(vuB.w);
            outB[0] = outB[0] * c + al * v0.x;
            outB[1] = outB[1] * c + al * v0.y;
            outB[2] = outB[2] * c + al * v1.x;
            outB[3] = outB[3] * c + al * v1.y;
            outB[4] = outB[4] * c + al * v2.x;
            outB[5] = outB[5] * c + al * v2.y;
            outB[6] = outB[6] * c + al * v3.x;
            outB[7] = outB[7] * c + al * v3.y;
            mB = m_new;
        }
    }
    if (i < deg) {  // tail edge -> state A
        int siA = __shfl(s_reg, i);
        int eiA = __shfl(e_reg, i);
        int sa = (siA < 0) ? 0 : siA;
        uint4 kuA = *(const uint4*)(kmat + (size_t)sa * HDIM + d0i);
        uint4 vuA = *(const uint4*)(vmat + (size_t)sa * HDIM + d0i);
        float eavA = eattr[(size_t)eiA * EDIMC + j];
        float2 ka0 = b2f2(kuA.x), ka1 = b2f2(kuA.y), ka2 = b2f2(kuA.z), ka3 = b2f2(kuA.w);
        float pA = qf[0] * ka0.x + qf[1] * ka0.y + qf[2] * ka1.x + qf[3] * ka1.y +
                   qf[4] * ka2.x + qf[5] * ka2.y + qf[6] * ka3.x + qf[7] * ka3.y;
        pA = fmaf(qWl, eavA, pA);
        pA += __shfl_xor(pA, 8);
        pA += __shfl_xor(pA, 4);
        pA += __shfl_xor(pA, 2);
        pA += __shfl_xor(pA, 1);
        float sA = (siA < 0) ? -1e30f : pA * SCALE;
        float m_new = fmaxf(mA, sA);
        float c = __expf(mA - m_new);
        float al = (siA < 0) ? 0.f : __expf(sA - m_new);
        denA = denA * c + al;
        zA = zA * c + al * eavA;
        float2 v0 = b2f2(vuA.x), v1 = b2f2(vuA.y), v2 = b2f2(vuA.z), v3 = b2f2(vuA.w);
        outA[0] = outA[0] * c + al * v0.x;
        outA[1] = outA[1] * c + al * v0.y;
        outA[2] = outA[2] * c + al * v1.x;
        outA[3] = outA[3] * c + al * v1.y;
        outA[4] = outA[4] * c + al * v2.x;
        outA[5] = outA[5] * c + al * v2.y;
        outA[6] = outA[6] * c + al * v3.x;
        outA[7] = outA[7] * c + al * v3.y;
        mA = m_new;
    }
    // exact merge of the two states
    float mT = fmaxf(mA, mB);
    float cA = __expf(mA - mT), cB = __expf(mB - mT);
    float den = denA * cA + denB * cB;
    float z = zA * cA + zB * cB;
    float out[8];
#pragma unroll
    for (int d = 0; d < 8; ++d) out[d] = outA[d] * cA + outB[d] * cB;

    float inv = 1.f / fmaxf(den, 1e-16f);
    z *= inv;
#pragma unroll
    for (int d = 0; d < 8; ++d) out[d] *= inv;

    // eproj
#pragma unroll
    for (int jj = 0; jj < EDIMC; ++jj) {
        float zjj = __shfl(z, h * 16 + jj);
        const float4* wp = (const float4*)(We + (size_t)jj * HDIM + d0i);
        float4 wa = wp[0], wb4 = wp[1];
        out[0] = fmaf(zjj, wa.x, out[0]);
        out[1] = fmaf(zjj, wa.y, out[1]);
        out[2] = fmaf(zjj, wa.z, out[2]);
        out[3] = fmaf(zjj, wa.w, out[3]);
        out[4] = fmaf(zjj, wb4.x, out[4]);
        out[5] = fmaf(zjj, wb4.y, out[5]);
        out[6] = fmaf(zjj, wb4.z, out[6]);
        out[7] = fmaf(zjj, wb4.w, out[7]);
    }

    // beta gate + gated combine
    uint4 xu = *(const uint4*)(xr + (size_t)n * HDIM + d0i);
    float2 x0 = b2f2(xu.x), x1 = b2f2(xu.y), x2 = b2f2(xu.z), x3 = b2f2(xu.w);
    float xf[8] = {x0.x, x0.y, x1.x, x1.y, x2.x, x2.y, x3.x, x3.y};
    const float4* w0p = (const float4*)(Wb + d0i);
    const float4* w1p = (const float4*)(Wb + HDIM + d0i);
    const float4* w2p = (const float4*)(Wb + 2 * HDIM + d0i);
    float4 wa0 = w0p[0], wa1 = w0p[1];
    float4 wb0 = w1p[0], wb1 = w1p[1];
    float4 wc0 = w2p[0], wc1 = w2p[1];
    float w0f[8] = {wa0.x, wa0.y, wa0.z, wa0.w, wa1.x, wa1.y, wa1.z, wa1.w};
    float w1f[8] = {wb0.x, wb0.y, wb0.z, wb0.w, wb1.x, wb1.y, wb1.z, wb1.w};
    float w2f[8] = {wc0.x, wc0.y, wc0.z, wc0.w, wc1.x, wc1.y, wc1.z, wc1.w};
    float part = 0.f;
#pragma unroll
    for (int d = 0; d < 8; ++d)
        part += out[d] * w0f[d] + xf[d] * w1f[d] + (out[d] - xf[d]) * w2f[d];
#pragma unroll
    for (int o = 32; o > 0; o >>= 1) part += __shfl_xor(part, o);
    float bg = 1.f / (1.f + __expf(-part));
    uint4 res;
    res.x = pack2(bg * xf[0] + (1.f - bg) * out[0], bg * xf[1] + (1.f - bg) * out[1]);
    res.y = pack2(bg * xf[2] + (1.f - bg) * out[2], bg * xf[3] + (1.f - bg) * out[3]);
    res.z = pack2(bg * xf[4] + (1.f - bg) * out[4], bg * xf[5] + (1.f - bg) * out[5]);
    res.w = pack2(bg * xf[6] + (1.f - bg) * out[6], bg * xf[7] + (1.f - bg) * out[7]);
    *(uint4*)(h2 + (size_t)n * HDIM + d0i) = res;
}

// ---------------- TopK pool, split for parallelism ----------------------------------
__global__ __launch_bounds__(256) void k_pool_rank(const float* __restrict__ pwv,
                                                   const float* __restrict__ h,
                                                   int* __restrict__ nmask,
                                                   int* __restrict__ emask,  // null => skip
                                                   const int* __restrict__ src,
                                                   const int* __restrict__ dst,
                                                   float* __restrict__ fbuf, int kc) {
    __shared__ float smS[NPGC];
    __shared__ int keepS[NPGC];
    int g = blockIdx.x, t = threadIdx.x;
    int n = g * NPGC + t;
    const float* hr = h + (size_t)n * FF;
    float nw2 = 0.f, dv = 0.f;
#pragma unroll
    for (int i = 0; i < FF; i += 4) {
        float4 wv = *(const float4*)(pwv + i);
        float4 hv = *(const float4*)(hr + i);
        nw2 += wv.x * wv.x + wv.y * wv.y + wv.z * wv.z + wv.w * wv.w;
        dv += hv.x * wv.x + hv.y * wv.y + hv.z * wv.z + hv.w * wv.w;
    }
    float s = tanhf(dv / sqrtf(nw2));
    int old = nmask[n];
    smS[t] = old ? s : -INFINITY;
    __syncthreads();
    float mys = smS[t];
    int rank = 0;
    for (int j = 0; j < NPGC; ++j) {
        float o = smS[j];
        rank += (o > mys) || (o == mys && j < t);  // stable argsort tie-break
    }
    int kp = (rank < kc) && old;  // ranks unique -> exactly kc kept per graph
    keepS[t] = kp;
    nmask[n] = kp;
    fbuf[n] = s * (float)kp;
    __syncthreads();
    if (emask) {
        int base = g * EGC;
        for (int ee = t; ee < EGC; ee += 256) {
            int e = base + ee;
            emask[e] = emask[e] && keepS[src[e] - g * NPGC] && keepS[dst[e] - g * NPGC];
        }
    }
}

// apply: grid (BB,4): scale, optional bf16 emit, per-dim max/sum partials (64 nodes).
__global__ __launch_bounds__(256) void k_pool_apply(const float* __restrict__ h,
                                                    unsigned short* __restrict__ hbf,
                                                    const float* __restrict__ fbuf,
                                                    const int* __restrict__ nmask,
                                                    float* __restrict__ pmax,
                                                    float* __restrict__ psum, int emit) {
    __shared__ float mS[4][128];
    __shared__ float sS[4][128];
    int g = blockIdx.x, seg = blockIdx.y, t = threadIdx.x;
    int l = t & 63, quar = t >> 6;
    int d2 = l * 2;
    int nbase = g * NPGC + seg * 64 + quar * 16;
    float mx0 = -1e30f, mx1 = -1e30f, sm0 = 0.f, sm1 = 0.f;
#pragma unroll 4
    for (int i = 0; i < 16; ++i) {
        int n = nbase + i;
        float f = fbuf[n];
        int kp = nmask[n];
        float2 hv = *(const float2*)(h + (size_t)n * FF + d2);
        float v0 = hv.x * f, v1 = hv.y * f;
        if (emit) *(unsigned*)(hbf + (size_t)n * FF + d2) = pack2(v0, v1);
        if (kp) {
            mx0 = fmaxf(mx0, v0);
            mx1 = fmaxf(mx1, v1);
            sm0 += v0;
            sm1 += v1;
        }
    }
    mS[quar][d2] = mx0;
    mS[quar][d2 + 1] = mx1;
    sS[quar][d2] = sm0;
    sS[quar][d2 + 1] = sm1;
    __syncthreads();
    if (t < 128) {
        float m = fmaxf(fmaxf(mS[0][t], mS[1][t]), fmaxf(mS[2][t], mS[3][t]));
        float s = sS[0][t] + sS[1][t] + sS[2][t] + sS[3][t];
        pmax[((size_t)g * 4 + seg) * 128 + t] = m;
        psum[((size_t)g * 4 + seg) * 128 + t] = s;
    }
}

// final 32x10 layer (fp32, tiny)
__global__ __launch_bounds__(256) void k_mlp_wave(const float* __restrict__ A,
                                                  const float* __restrict__ W,
                                                  const float* __restrict__ b,
                                                  float* __restrict__ C,
                                                  int M, int N, int K, int relu) {
    int wid = (blockIdx.x * 256 + threadIdx.x) >> 6;
    int lane = threadIdx.x & 63;
    if (wid >= M * N) return;
    int r = wid / N, c = wid % N;
    const float* Arow = A + (size_t)r * K;
    float acc = 0.f;
    for (int kk = lane; kk < K; kk += 64)
        acc = fmaf(Arow[kk], W[(size_t)kk * N + c], acc);
    acc = waveReduceSum(acc);
    if (lane == 0) {
        acc += b[c];
        C[wid] = relu ? fmaxf(acc, 0.f) : acc;
    }
}

// ---------------- host launch ----------------
extern "C" void kernel_launch(void* const* d_in, const int* in_sizes, int n_in,
                              void* d_out, int out_size, void* d_ws, size_t ws_size,
                              hipStream_t stream) {
    const float* x = (const float*)d_in[0];
    const float* eattr = (const float*)d_in[1];
    const int* eidx = (const int*)d_in[2];
    const float* esm = (const float*)d_in[4];
    const float* Wq = (const float*)d_in[5];
    const float* bq = (const float*)d_in[6];
    const float* Wk = (const float*)d_in[7];
    const float* bk = (const float*)d_in[8];
    const float* Wv = (const float*)d_in[9];
    const float* bv = (const float*)d_in[10];
    const float* We = (const float*)d_in[11];
    const float* Wsk = (const float*)d_in[12];
    const float* bsk = (const float*)d_in[13];
    const float* Wbe = (const float*)d_in[14];
    const float* Wt = (const float*)d_in[15];
    const float* bt = (const float*)d_in[16];
    const float* gam = (const float*)d_in[17];
    const float* bet = (const float*)d_in[18];
    const float* rme = (const float*)d_in[19];
    const float* rva = (const float*)d_in[20];
    const float* pw = (const float*)d_in[21];
    const float* W1 = (const float*)d_in[22];
    const float* b1 = (const float*)d_in[23];
    const float* W2 = (const float*)d_in[24];
    const float* b2 = (const float*)d_in[25];
    const float* W3 = (const float*)d_in[26];
    const float* b3 = (const float*)d_in[27];
    const int* srcp = eidx;
    const int* dstp = eidx + NEDGE;

    char* p = (char*)d_ws;
    auto alloc = [&](size_t bytes) -> void* {
        void* r = (void*)p;
        p += (bytes + 255) & ~(size_t)255;
        return r;
    };
    float* hB = (float*)alloc((size_t)NNODE * FF * 4);
    float* fbuf = (float*)alloc((size_t)NNODE * 4);
    float* pmax0 = (float*)alloc((size_t)BB * 4 * 128 * 4);
    float* psum0 = (float*)alloc((size_t)BB * 4 * 128 * 4);
    float* pmax1 = (float*)alloc((size_t)BB * 4 * 128 * 4);
    float* psum1 = (float*)alloc((size_t)BB * 4 * 128 * 4);
    float* g2 = (float*)alloc((size_t)BB * 512 * 4);
    float* g3 = (float*)alloc((size_t)BB * 256 * 4);
    float* cp = (float*)alloc((size_t)8 * 32 * 512 * 4);
    int* nmask = (int*)alloc((size_t)NNODE * 4);
    int* emask = (int*)alloc((size_t)NEDGE * 4);
    int* coff = (int*)alloc((size_t)(NNODE + 1) * 4);
    int* ceid = (int*)alloc((size_t)NEDGE * 4);
    // bf16 buffers
    unsigned short* xb = (unsigned short*)alloc((size_t)NNODE * FF * 2);
    unsigned short* hbf = (unsigned short*)alloc((size_t)NNODE * FF * 2);
    unsigned short* qb16 = (unsigned short*)alloc((size_t)NNODE * HDIM * 2);
    unsigned short* kb16 = (unsigned short*)alloc((size_t)NNODE * HDIM * 2);
    unsigned short* vb16 = (unsigned short*)alloc((size_t)NNODE * HDIM * 2);
    unsigned short* xrb16 = (unsigned short*)alloc((size_t)NNODE * HDIM * 2);
    unsigned short* h2b16 = (unsigned short*)alloc((size_t)NNODE * HDIM * 2);
    unsigned short* wqb = (unsigned short*)alloc((size_t)4 * 65536 * 2);
    unsigned short* wkb = (unsigned short*)alloc((size_t)4 * 65536 * 2);
    unsigned short* wvb = (unsigned short*)alloc((size_t)4 * 65536 * 2);
    unsigned short* wskb = (unsigned short*)alloc((size_t)4 * 65536 * 2);
    unsigned short* wtb = (unsigned short*)alloc((size_t)4 * 65536 * 2);
    unsigned short* w1b = (unsigned short*)alloc((size_t)786432 * 2);
    unsigned short* w2b = (unsigned short*)alloc((size_t)131072 * 2);
    unsigned short* g1b = (unsigned short*)alloc((size_t)BB * 1536 * 2);
    unsigned short* g2b = (unsigned short*)alloc((size_t)BB * 512 * 2);

    k_convert_setup<<<12832, 256, 0, stream>>>(x, Wq, Wk, Wv, Wsk, Wt, W1, W2,
                                               xb, wqb, wkb, wvb, wskb, wtb, w1b, w2b,
                                               dstp, emask, nmask, coff, ceid);

    auto conv = [&](int li, const unsigned short* hin_b, float* hout) {
        dim3 gq(64, 4, 4);
        k_qkvs_mfma<<<gq, 256, 0, stream>>>(
            hin_b, wqb + (size_t)li * 65536, wkb + (size_t)li * 65536,
            wvb + (size_t)li * 65536, wskb + (size_t)li * 65536,
            bq + li * HDIM, bk + li * HDIM, bv + li * HDIM, bsk + li * HDIM,
            qb16, kb16, vb16, xrb16);
        const float* WeL = We + (size_t)li * EDIMC * HDIM;
        k_attn_wave<<<NNODE / 4, 256, 0, stream>>>(qb16, kb16, vb16, xrb16, eattr, WeL,
                                                   Wbe + (size_t)li * 3 * HDIM,
                                                   srcp, coff, ceid, emask, h2b16);
        k_out_mfma<<<NNODE / 32, 128, 0, stream>>>(
            h2b16, wtb + (size_t)li * 65536, bt + li * FF, gam + li * FF,
            bet + li * FF, rme + li * FF, rva + li * FF, hout, hbf);
    };

    auto pool = [&](int pi, const float* h, float* pmax, float* psum, int kc, bool updE,
                    int emit) {
        k_pool_rank<<<BB, 256, 0, stream>>>(pw + pi * FF, h, nmask,
                                            updE ? emask : nullptr, srcp, dstp, fbuf, kc);
        k_pool_apply<<<dim3(BB, 4), 256, 0, stream>>>(h, hbf, fbuf, nmask, pmax, psum, emit);
    };

    // layer 4 of the reference is dead code (output feeds nothing) — skipped.
    // fp32 h is only consumed by the pools (layers 1 and 3); layers 0/2 skip it.
    conv(0, xb, nullptr);
    conv(1, hbf, hB);
    pool(0, hB, pmax0, psum0, NPGC / 2, true, 1);   // emits bf16 h for conv2
    conv(2, hbf, nullptr);
    conv(3, hbf, hB);
    pool(1, hB, pmax1, psum1, NPGC / 4, false, 0);  // nothing downstream reads h

    k_g1<<<BB * 1536 / 256, 256, 0, stream>>>(pmax0, psum0, pmax1, psum1, esm, g1b);
    k_mlp_mfma<<<dim3(2, 8), 256, 0, stream>>>(g1b, w1b, cp, 512, 1536, 8);
    k_mlp_fix<<<BB * 512 / 256, 256, 0, stream>>>(cp, b1, g2, g2b, BB * 512, 512, 8, 1);
    k_mlp_mfma<<<dim3(1, 8), 256, 0, stream>>>(g2b, w2b, cp, 256, 512, 8);
    k_mlp_fix<<<BB * 256 / 256, 256, 0, stream>>>(cp, b2, g3, nullptr, BB * 256, 256, 8, 1);
    k_mlp_wave<<<(BB * 10 * 64 + 255) / 256, 256, 0, stream>>>(g3, W3, b3, (float*)d_out,
                                                               BB, 10, 256, 0);
}